// Round 4
// baseline (7396.404 us; speedup 1.0000x reference)
//
#include <hip/hip_runtime.h>
#include <cstdint>
#include <cstddef>

typedef unsigned short u16;
typedef unsigned long long u64;
typedef __attribute__((ext_vector_type(8))) short s16x8;
typedef __attribute__((ext_vector_type(4))) float f32x4;
typedef __attribute__((ext_vector_type(4))) unsigned short u16x4;

#define AGENT __HIP_MEMORY_SCOPE_AGENT

namespace {
constexpr int NWG  = 256;
constexpr int NTHR = 256;
constexpr int Bb   = 256;   // batch
constexpr int Tt   = 256;   // timesteps
constexpr int EMB_ = 256;
constexpr int HID_ = 512;
constexpr int NCLS = 32000;

// ---- LDS layout (bytes). B-operands stored in MFMA lane order:
//      elem addr = ((kb*NT + n)*64 + lane)*8 + e  -> ds_read_b128 lane-linear, 0 conflicts
constexpr int OFF_W1  = 0;        // cell1 [24 kb][2 n][64 lane][8] = 49152 B
constexpr int OFF_W3  = 49152;    // cell2, same shape
constexpr int OFF_W2  = 98304;    // mix   [32 kb][1 n][64][8]     = 32768 B
constexpr int OFF_DS  = 131072;   // cell2 gate scratch [64][33] f32 = 8448 B
constexpr int OFF_DS1 = 139520;   // cell1 gate scratch [64][33] f32 = 8448 B
constexpr int OFF_DSM = 147968;   // mix per-wave transpose 2 x [16][17] f32 = 2176 B
constexpr int OFF_C   = 150144;   // cell1 C state [64][8] f32 (bq reuse in final)
constexpr int OFF_C1  = 152192;   // cell2 C state
constexpr int OFF_B1  = 154240;
constexpr int OFF_B3  = 154368;
constexpr int OFF_B2  = 154496;
constexpr int SMEM_BYTES = 154560;            // 1 WG/CU

// ---- workspace layout (bytes) ----
constexpr size_t WS_FL   = 0;                          // 256 WGs x 128 B = 32 KB
constexpr size_t WS_DONE = 32768;                      // 256 int done flags (one-time)
constexpr size_t WS_HB0  = 33792;                      // H parity buffers [B][512] bf16
constexpr size_t WS_HB1  = WS_HB0 + (size_t)Bb * HID_ * 2;
constexpr size_t WS_H1   = WS_HB1 + (size_t)Bb * HID_ * 2;   // H1 state
constexpr size_t WS_HM   = WS_H1 + (size_t)Bb * HID_ * 2;    // H1mix
constexpr size_t WS_XE   = WS_HM + (size_t)Bb * HID_ * 2;    // Xe [T][B][EMB] bf16
}  // namespace

struct Params {
  const int* X; const float* Hin; const float* Cin; const float* E;
  const float* Wx[4];  const float* Wh[4];  const float* bg[4];   // cell 1 (i,f,o,c)
  const float* Wx1[4]; const float* Wh1[4]; const float* bg1[4];  // cell 2
  const float* Wxh; const float* Whh; const float* bh;
  const float* Whq; const float* bq;
  float* out; char* ws;
};

__device__ __forceinline__ u16 f2bf(float f) {
  union { float f; unsigned u; } v; v.f = f;
  unsigned r = v.u + 0x7FFFu + ((v.u >> 16) & 1u);
  return (u16)(r >> 16);
}
__device__ __forceinline__ float sigm(float x) { return 1.f / (1.f + __expf(-x)); }
__device__ __forceinline__ float tanh_(float x) {
  x = fminf(fmaxf(x, -10.f), 10.f);
  float e = __expf(-2.f * x);
  return (1.f - e) / (1.f + e);
}
__device__ __forceinline__ f32x4 mfma16(s16x8 a, s16x8 b, f32x4 c) {
  return __builtin_amdgcn_mfma_f32_16x16x32_bf16(a, b, c, 0, 0, 0);
}

// ---- producer side: LLC-coherent bypass stores (relaxed agent atomics).
// Data is at the Infinity Cache before the flag store (syncthreads drains vmcnt).
__device__ __forceinline__ void st8_llc(u16* p2, u64 v) {
  __hip_atomic_store((u64*)p2, v, __ATOMIC_RELAXED, AGENT);
}

// ---- consumer side: NORMAL CACHED loads. Coherence via per-phase agent
// acquire fence in waitbar (bulk L1/L2 invalidate; steady state has zero
// normal stores -> no dirty lines -> invalidate is cheap, no writeback).
// Payoff: 8 WGs of a group share an XCD's L2 -> one LLC fill serves 8 WGs,
// 64B granule instead of 8B -> ~8x less fabric traffic than bypass loads.

// Split barrier: arrive (after our stores drained by __syncthreads' vmcnt(0)) /
// waitbar (poll all 64 flags, then acquire-inv so cached loads see fresh data).
__device__ __forceinline__ void arrive(int* fl, int slot, int ph) {
  __syncthreads();
  if (threadIdx.x == 0)
    __hip_atomic_store(&fl[slot * 32], ph, __ATOMIC_RELAXED, AGENT);
}
__device__ __forceinline__ void waitbar(int* fl, int ph) {
  if (threadIdx.x < 64) {
    for (;;) {
      int v = __hip_atomic_load(&fl[threadIdx.x * 32], __ATOMIC_RELAXED, AGENT);
      if (!__any(v < ph)) break;
      __builtin_amdgcn_s_sleep(1);
    }
  }
  __syncthreads();
  __builtin_amdgcn_fence(__ATOMIC_ACQUIRE, "agent");   // inv L1/L2 (clean) -> cached loads coherent
}

// Heavy barrier (release store + agent acquire fence -> wbl2/inv). Used ONCE
// after init (publishes normal-stored Xe/H-init).
__device__ __forceinline__ void groupbar_heavy(int* fl, int slot, int ph) {
  __syncthreads();
  if (threadIdx.x == 0)
    __hip_atomic_store(&fl[slot * 32], ph, __ATOMIC_RELEASE, AGENT);
  if (threadIdx.x < 64) {
    for (;;) {
      int v = __hip_atomic_load(&fl[threadIdx.x * 32], __ATOMIC_RELAXED, AGENT);
      if (!__any(v < ph)) break;
      __builtin_amdgcn_s_sleep(1);
    }
  }
  __syncthreads();
  __builtin_amdgcn_fence(__ATOMIC_ACQUIRE, "agent");
}

// One-time all-grid done wait (before the final GEMM). Heavy on purpose: its
// acquire-inv lets the final GEMM use normal cached loads on H1b.
__device__ __forceinline__ void donebar(int* dn, int bi) {
  __syncthreads();
  if (threadIdx.x == 0)
    __hip_atomic_store(&dn[bi], 1, __ATOMIC_RELEASE, AGENT);
  for (;;) {
    int v = __hip_atomic_load(&dn[threadIdx.x], __ATOMIC_RELAXED, AGENT);
    if (!__any(v < 1)) break;
    __builtin_amdgcn_s_sleep(1);
  }
  __syncthreads();
  __builtin_amdgcn_fence(__ATOMIC_ACQUIRE, "agent");
}

// Single-cell phase (prologue cell1(0) only; 4 waves, full syncthreads handoff).
__device__ __forceinline__ void cell_phase(char* smem, int offW, int offB, int offC,
                                           const u16* Xt, const u16* Hrec, u16* Hdst,
                                           int g, int c, int w, int lane, int tid) {
  const int r = lane & 15, q = lane >> 4;
  const int row0 = w * 16;
  const u16* xrow = Xt + (size_t)(g * 64 + row0 + r) * EMB_;
  const u16* hrow = Hrec + (size_t)(g * 64 + row0 + r) * HID_;
  const u16* wb = (const u16*)(smem + offW) + lane * 8;
  f32x4 acc0 = {0.f, 0.f, 0.f, 0.f}, acc1 = {0.f, 0.f, 0.f, 0.f};
#pragma unroll
  for (int kb = 0; kb < 8; kb++) {                    // x_t part of K (256)
    s16x8 a  = *(const s16x8*)(xrow + kb * 32 + q * 8);
    s16x8 b0 = *(const s16x8*)(wb + (size_t)(kb * 2 + 0) * 512);
    s16x8 b1 = *(const s16x8*)(wb + (size_t)(kb * 2 + 1) * 512);
    acc0 = mfma16(a, b0, acc0);
    acc1 = mfma16(a, b1, acc1);
  }
  s16x8 ha[16];
#pragma unroll
  for (int kb = 0; kb < 16; kb++) ha[kb] = *(const s16x8*)(hrow + kb * 32 + q * 8);
#pragma unroll
  for (int kb = 0; kb < 16; kb++) {                   // recurrent part of K (512)
    s16x8 b0 = *(const s16x8*)(wb + (size_t)((kb + 8) * 2 + 0) * 512);
    s16x8 b1 = *(const s16x8*)(wb + (size_t)((kb + 8) * 2 + 1) * 512);
    acc0 = mfma16(ha[kb], b0, acc0);
    acc1 = mfma16(ha[kb], b1, acc1);
  }
  float* Ds = (float*)(smem + OFF_DS);
#pragma unroll
  for (int i = 0; i < 4; i++) {
    Ds[(row0 + q * 4 + i) * 33 + r]      = acc0[i];
    Ds[(row0 + q * 4 + i) * 33 + 16 + r] = acc1[i];
  }
  __syncthreads();
  const float* bs = (const float*)(smem + offB);
  float* Cs = (float*)(smem + offC);
  if (tid < 128) {
    int row = tid >> 1, j0 = (tid & 1) * 4;
    union { u16 h[4]; u64 qv; } pk;
#pragma unroll
    for (int i = 0; i < 4; i++) {
      int j = j0 + i;
      float vi = Ds[row * 33 + 0 + j]  + bs[0 + j];
      float vf = Ds[row * 33 + 8 + j]  + bs[8 + j];
      float vo = Ds[row * 33 + 16 + j] + bs[16 + j];
      float vc = Ds[row * 33 + 24 + j] + bs[24 + j];
      float I = sigm(vi), F = sigm(vf), O = sigm(vo), Ct = tanh_(vc);
      float Cn = F * Cs[row * 8 + j] + I * Ct;
      Cs[row * 8 + j] = Cn;
      pk.h[i] = f2bf(O * tanh_(Cn));
    }
    st8_llc(Hdst + (size_t)(g * 64 + row) * HID_ + c * 8 + j0, pk.qv);
  }
}

// cell1 on waves 2-3 only: full gate GEMM + elementwise + H-store, no barrier.
// Wave wv ({0,1} = tid>>6 - 2) owns rows wv*32..+31; scratch handoff is
// intra-wave (lgkmcnt only). Runs entirely PRE-wait inside phase B.
__device__ __forceinline__ void cell1_w23(char* smem, const u16* Xt, const u16* Hrec,
                                          u16* Hdst, int g, int c, int lane, int tid) {
  const int wv = (tid >> 6) - 2;
  const int r = lane & 15, q = lane >> 4;
  const u16* wb1 = (const u16*)(smem + OFF_W1) + lane * 8;
  float* D1 = (float*)(smem + OFF_DS1);
#pragma unroll
  for (int blk = 0; blk < 2; blk++) {
    const int rb = wv * 32 + blk * 16;
    const u16* xrow = Xt + (size_t)(g * 64 + rb + r) * EMB_;
    const u16* hrow = Hrec + (size_t)(g * 64 + rb + r) * HID_;
    s16x8 xa[8];
#pragma unroll
    for (int kb = 0; kb < 8; kb++) xa[kb] = *(const s16x8*)(xrow + kb * 32 + q * 8);
    s16x8 hh[16];
#pragma unroll
    for (int kb = 0; kb < 16; kb++) hh[kb] = *(const s16x8*)(hrow + kb * 32 + q * 8);
    f32x4 a0 = {0.f, 0.f, 0.f, 0.f}, a1 = {0.f, 0.f, 0.f, 0.f};
#pragma unroll
    for (int kb = 0; kb < 8; kb++) {
      a0 = mfma16(xa[kb], *(const s16x8*)(wb1 + (size_t)(kb * 2 + 0) * 512), a0);
      a1 = mfma16(xa[kb], *(const s16x8*)(wb1 + (size_t)(kb * 2 + 1) * 512), a1);
    }
#pragma unroll
    for (int kb = 0; kb < 16; kb++) {
      a0 = mfma16(hh[kb], *(const s16x8*)(wb1 + (size_t)((kb + 8) * 2 + 0) * 512), a0);
      a1 = mfma16(hh[kb], *(const s16x8*)(wb1 + (size_t)((kb + 8) * 2 + 1) * 512), a1);
    }
#pragma unroll
    for (int i = 0; i < 4; i++) {
      D1[(rb + q * 4 + i) * 33 + r]      = a0[i];
      D1[(rb + q * 4 + i) * 33 + 16 + r] = a1[i];
    }
  }
  // elementwise: wave wv reads rows wv*32..+31, which it wrote (intra-wave)
  const float* bs = (const float*)(smem + OFF_B1);
  float* Cs = (float*)(smem + OFF_C);
  int t2 = tid - 128;
  int row = t2 >> 1, j0 = (t2 & 1) * 4;
  union { u16 h[4]; u64 qv; } pk;
#pragma unroll
  for (int i = 0; i < 4; i++) {
    int j = j0 + i;
    float vi = D1[row * 33 + 0 + j]  + bs[0 + j];
    float vf = D1[row * 33 + 8 + j]  + bs[8 + j];
    float vo = D1[row * 33 + 16 + j] + bs[16 + j];
    float vc = D1[row * 33 + 24 + j] + bs[24 + j];
    float I = sigm(vi), F = sigm(vf), O = sigm(vo), Ct = tanh_(vc);
    float Cn = F * Cs[row * 8 + j] + I * Ct;
    Cs[row * 8 + j] = Cn;
    pk.h[i] = f2bf(O * tanh_(Cn));
  }
  st8_llc(Hdst + (size_t)(g * 64 + row) * HID_ + c * 8 + j0, pk.qv);
}

// mix part 1 (pre-wait): acc = H(t+1) @ W_xh  (waves 0-1 only)
__device__ __forceinline__ f32x4 mix_part1(char* smem, const u16* Hnew, int g, int c,
                                           int w, int lane) {
  const int r = lane & 15, q = lane >> 4;
  int rbase = g * 64 + (c & 1) * 32 + w * 16 + r;
  const u16* h0 = Hnew + (size_t)rbase * HID_;
  const u16* wb = (const u16*)(smem + OFF_W2) + lane * 8;
  s16x8 ha[16];
#pragma unroll
  for (int kb = 0; kb < 16; kb++) ha[kb] = *(const s16x8*)(h0 + kb * 32 + q * 8);
  f32x4 acc = {0.f, 0.f, 0.f, 0.f};
#pragma unroll
  for (int kb = 0; kb < 16; kb++)
    acc = mfma16(ha[kb], *(const s16x8*)(wb + (size_t)kb * 512), acc);
  return acc;
}

// mix part 2 (post-wait): acc += H1(t) @ W_hh; sigmoid; store H1m.
// Output transpose via per-wave private LDS (intra-wave, no barrier).
__device__ __forceinline__ void mix_part2(char* smem, f32x4 acc, const u16* H1old,
                                          u16* H1m, int g, int c, int w, int lane) {
  const int r = lane & 15, q = lane >> 4;
  int rbase = g * 64 + (c & 1) * 32 + w * 16 + r;
  const u16* h1 = H1old + (size_t)rbase * HID_;
  const u16* wb = (const u16*)(smem + OFF_W2) + lane * 8;
  s16x8 hb[16];
#pragma unroll
  for (int kb = 0; kb < 16; kb++) hb[kb] = *(const s16x8*)(h1 + kb * 32 + q * 8);
#pragma unroll
  for (int kb = 0; kb < 16; kb++)
    acc = mfma16(hb[kb], *(const s16x8*)(wb + (size_t)(16 + kb) * 512), acc);
  float* Dm = (float*)(smem + OFF_DSM) + (size_t)w * 16 * 17;
#pragma unroll
  for (int i = 0; i < 4; i++) Dm[(q * 4 + i) * 17 + r] = acc[i];
  const float* b2 = (const float*)(smem + OFF_B2);
  int row2 = lane >> 2, j0 = (lane & 3) * 4;
  union { u16 h[4]; u64 qv; } pk;
#pragma unroll
  for (int i = 0; i < 4; i++)
    pk.h[i] = f2bf(sigm(Dm[row2 * 17 + j0 + i] + b2[j0 + i]));
  st8_llc(H1m + (size_t)(g * 64 + (c & 1) * 32 + w * 16 + row2) * HID_ + (c >> 1) * 16 + j0,
          pk.qv);
}

__global__ __launch_bounds__(NTHR, 1) void lstm_pers(Params p) {
  extern __shared__ char smem[];
  const int tid = threadIdx.x;
  const int bi = blockIdx.x;
  const int w = tid >> 6, lane = tid & 63;
  const int g = bi >> 6, c = bi & 63;
  const int r = lane & 15, q = lane >> 4;

  int* fl = (int*)(p.ws + WS_FL) + g * 64 * 32;   // padded: one line per WG
  int* dn = (int*)(p.ws + WS_DONE);
  u16* Hb0 = (u16*)(p.ws + WS_HB0);
  u16* Hb1 = (u16*)(p.ws + WS_HB1);
  u16* H1b = (u16*)(p.ws + WS_H1);
  u16* H1m = (u16*)(p.ws + WS_HM);
  u16* Xe  = (u16*)(p.ws + WS_XE);

  // ---- one-time init: weights -> LDS (bf16, MFMA lane-order swizzle) ----
  {
    u16* w1 = (u16*)(smem + OFF_W1);
    u16* w3 = (u16*)(smem + OFF_W3);
    int gate = tid >> 6, kk8 = (tid >> 3) & 7, j = tid & 7;
    int cc = gate * 8 + j;          // col 0..31 (i0..7,f0..7,o0..7,c0..7)
    int n = cc >> 4, rr = cc & 15;
    int hid = c * 8 + j;
    for (int kk = kk8; kk < 768; kk += 8) {
      int kb = kk >> 5, q2 = (kk >> 3) & 3, e = kk & 7;
      size_t dst = ((size_t)(kb * 2 + n) * 64 + q2 * 16 + rr) * 8 + e;
      float s1 = (kk < 256) ? p.Wx[gate][(size_t)kk * HID_ + hid]
                            : p.Wh[gate][(size_t)(kk - 256) * HID_ + hid];
      float s3 = (kk < 256) ? p.Wx1[gate][(size_t)kk * HID_ + hid]
                            : p.Wh1[gate][(size_t)(kk - 256) * HID_ + hid];
      w1[dst] = f2bf(s1);
      w3[dst] = f2bf(s3);
    }
    {  // mix weights: every WG holds cols (c>>1)*16..+15 (pairs share)
      u16* w2 = (u16*)(smem + OFF_W2);
      int kk16 = tid >> 4, j2 = tid & 15;
      int hid2 = (c >> 1) * 16 + j2;
      for (int kk = kk16; kk < 1024; kk += 16) {
        int kb = kk >> 5, q2 = (kk >> 3) & 3, e = kk & 7;
        size_t dst = ((size_t)kb * 64 + q2 * 16 + j2) * 8 + e;
        float s = (kk < 512) ? p.Wxh[(size_t)kk * HID_ + hid2]
                             : p.Whh[(size_t)(kk - 512) * HID_ + hid2];
        w2[dst] = f2bf(s);
      }
      if (tid < 16) ((float*)(smem + OFF_B2))[tid] = p.bh[(c >> 1) * 16 + tid];
    }
    if (tid < 32) {
      int gt = tid >> 3, jj = tid & 7;
      ((float*)(smem + OFF_B1))[tid] = p.bg[gt][c * 8 + jj];
      ((float*)(smem + OFF_B3))[tid] = p.bg1[gt][c * 8 + jj];
    }
    // C / C1 state (fp32, LDS-resident, WG-local forever)
    float* Cs = (float*)(smem + OFF_C);
    float* C1s = (float*)(smem + OFF_C1);
    for (int it = 0; it < 2; it++) {
      int idx = tid + it * 256;
      int row = idx >> 3, j8 = idx & 7;
      float v = p.Cin[(size_t)(g * 64 + row) * HID_ + c * 8 + j8];
      Cs[row * 8 + j8] = v;
      C1s[row * 8 + j8] = v;
    }
  }
  // H / H1 state init (bf16 in ws, normal stores -> published by heavy barrier)
  // Convention: H(t) lives in Hb[t&1]; H(-1)=Hin in Hb1.
  for (int it = 0; it < 2; it++) {
    int idx = bi * 512 + tid + it * 256;
    u16 hv = f2bf(p.Hin[idx]);
    Hb1[idx] = hv;
    H1b[idx] = hv;
  }
  // Embedding gather, group-local: WG (g,c) fills Xe[t=4c..4c+3][g*64..+63][:]
  for (int tt = 0; tt < 4; tt++) {
    int t0 = c * 4 + tt;
    for (int pp = 0; pp < 16; pp++) {
      int b = g * 64 + w * 16 + pp;
      int tok = p.X[(size_t)b * Tt + t0];
      const float4* er = (const float4*)(p.E + (size_t)tok * EMB_);
      float4 v = er[lane];
      u16x4 u; u.x = f2bf(v.x); u.y = f2bf(v.y); u.z = f2bf(v.z); u.w = f2bf(v.w);
      *(u16x4*)(Xe + ((size_t)t0 * Bb + b) * EMB_ + lane * 4) = u;
    }
  }
  int ph = 0;
  groupbar_heavy(fl, c, ++ph);   // ph=1: publish init data

  // ---- P0: cell1(0): H(-1)=Hb1 -> H(0)=Hb0 ----
  cell_phase(smem, OFF_W1, OFF_B1, OFF_C, Xe, Hb1, Hb0, g, c, w, lane, tid);
  arrive(fl, c, ++ph);           // ph=2

  // ---- P1: mix(0) [waves 0-1] + cell1(1) [waves 2-3] ----
  waitbar(fl, ph);
  if (w < 2) {
    f32x4 macc = mix_part1(smem, Hb0, g, c, w, lane);   // H(0) @ W_xh
    mix_part2(smem, macc, H1b, H1m, g, c, w, lane);     // + H1(-1) @ W_hh
  } else {
    cell1_w23(smem, Xe + (size_t)1 * Bb * EMB_, Hb0, Hb1, g, c, lane, tid);  // H(0)->H(1)
  }
  arrive(fl, c, ++ph);           // ph=3

  // ---- steady state: 2 thin phases per timestep ----
  for (int t = 0; t < Tt - 1; t++) {
    const u16* Xt = Xe + (size_t)t * Bb * EMB_;
    // ---------- Phase A_t: cell2(t) ----------
    {
      const u16* wb3 = (const u16*)(smem + OFF_W3) + lane * 8;
      const u16* xrow = Xt + (size_t)(g * 64 + w * 16 + r) * EMB_;
      f32x4 acc0 = {0.f, 0.f, 0.f, 0.f}, acc1 = {0.f, 0.f, 0.f, 0.f};
      s16x8 xa[8];
#pragma unroll
      for (int kb = 0; kb < 8; kb++) xa[kb] = *(const s16x8*)(xrow + kb * 32 + q * 8);
#pragma unroll
      for (int kb = 0; kb < 8; kb++) {     // x-part pre-wait
        acc0 = mfma16(xa[kb], *(const s16x8*)(wb3 + (size_t)(kb * 2 + 0) * 512), acc0);
        acc1 = mfma16(xa[kb], *(const s16x8*)(wb3 + (size_t)(kb * 2 + 1) * 512), acc1);
      }
      waitbar(fl, ph);                     // need H1m(t) from B_{t-1}; acquire-inv
      const u16* hrow = H1m + (size_t)(g * 64 + w * 16 + r) * HID_;
      s16x8 ha[16];
#pragma unroll
      for (int kb = 0; kb < 16; kb++) ha[kb] = *(const s16x8*)(hrow + kb * 32 + q * 8);
#pragma unroll
      for (int kb = 0; kb < 16; kb++) {
        acc0 = mfma16(ha[kb], *(const s16x8*)(wb3 + (size_t)((kb + 8) * 2 + 0) * 512), acc0);
        acc1 = mfma16(ha[kb], *(const s16x8*)(wb3 + (size_t)((kb + 8) * 2 + 1) * 512), acc1);
      }
      float* Ds = (float*)(smem + OFF_DS);
#pragma unroll
      for (int i = 0; i < 4; i++) {
        Ds[(w * 16 + q * 4 + i) * 33 + r]      = acc0[i];
        Ds[(w * 16 + q * 4 + i) * 33 + 16 + r] = acc1[i];
      }
      __syncthreads();
      if (tid < 128) {
        const float* bs = (const float*)(smem + OFF_B3);
        float* Cs = (float*)(smem + OFF_C1);
        int row = tid >> 1, j0 = (tid & 1) * 4;
        union { u16 h[4]; u64 qv; } pk;
#pragma unroll
        for (int i = 0; i < 4; i++) {
          int j = j0 + i;
          float vi = Ds[row * 33 + 0 + j]  + bs[0 + j];
          float vf = Ds[row * 33 + 8 + j]  + bs[8 + j];
          float vo = Ds[row * 33 + 16 + j] + bs[16 + j];
          float vc = Ds[row * 33 + 24 + j] + bs[24 + j];
          float I = sigm(vi), F = sigm(vf), O = sigm(vo), Ct = tanh_(vc);
          float Cn = F * Cs[row * 8 + j] + I * Ct;
          Cs[row * 8 + j] = Cn;
          pk.h[i] = f2bf(O * tanh_(Cn));
        }
        st8_llc(H1b + (size_t)(g * 64 + row) * HID_ + c * 8 + j0, pk.qv);
      }
      arrive(fl, c, ++ph);
    }
    // ---------- Phase B_t: mix(t+1) [w 0-1] + cell1(t+2) [w 2-3, pre-wait] ----------
    {
      const u16* Hnew = (t & 1) ? Hb0 : Hb1;   // H(t+1)
      u16* Hdst1      = (t & 1) ? Hb1 : Hb0;   // H(t+2)
      f32x4 macc = {0.f, 0.f, 0.f, 0.f};
      if (w < 2) {
        macc = mix_part1(smem, Hnew, g, c, w, lane);        // pre-wait half
      } else if (t + 2 < Tt) {
        cell1_w23(smem, Xe + (size_t)(t + 2) * Bb * EMB_, Hnew, Hdst1, g, c, lane, tid);
      }
      waitbar(fl, ph);                       // need H1(t) from A_t; acquire-inv
      if (w < 2) mix_part2(smem, macc, H1b, H1m, g, c, w, lane);
      arrive(fl, c, ++ph);
    }
  }

  // ---- epilogue: cell2(255) ----
  {
    const u16* Xt = Xe + (size_t)(Tt - 1) * Bb * EMB_;
    const u16* wb3 = (const u16*)(smem + OFF_W3) + lane * 8;
    const u16* xrow = Xt + (size_t)(g * 64 + w * 16 + r) * EMB_;
    f32x4 acc0 = {0.f, 0.f, 0.f, 0.f}, acc1 = {0.f, 0.f, 0.f, 0.f};
    s16x8 xa[8];
#pragma unroll
    for (int kb = 0; kb < 8; kb++) xa[kb] = *(const s16x8*)(xrow + kb * 32 + q * 8);
#pragma unroll
    for (int kb = 0; kb < 8; kb++) {
      acc0 = mfma16(xa[kb], *(const s16x8*)(wb3 + (size_t)(kb * 2 + 0) * 512), acc0);
      acc1 = mfma16(xa[kb], *(const s16x8*)(wb3 + (size_t)(kb * 2 + 1) * 512), acc1);
    }
    waitbar(fl, ph);                         // mix(255) from B_254; acquire-inv
    const u16* hrow = H1m + (size_t)(g * 64 + w * 16 + r) * HID_;
    s16x8 ha[16];
#pragma unroll
    for (int kb = 0; kb < 16; kb++) ha[kb] = *(const s16x8*)(hrow + kb * 32 + q * 8);
#pragma unroll
    for (int kb = 0; kb < 16; kb++) {
      acc0 = mfma16(ha[kb], *(const s16x8*)(wb3 + (size_t)((kb + 8) * 2 + 0) * 512), acc0);
      acc1 = mfma16(ha[kb], *(const s16x8*)(wb3 + (size_t)((kb + 8) * 2 + 1) * 512), acc1);
    }
    float* Ds = (float*)(smem + OFF_DS);
#pragma unroll
    for (int i = 0; i < 4; i++) {
      Ds[(w * 16 + q * 4 + i) * 33 + r]      = acc0[i];
      Ds[(w * 16 + q * 4 + i) * 33 + 16 + r] = acc1[i];
    }
    __syncthreads();
    if (tid < 128) {
      const float* bs = (const float*)(smem + OFF_B3);
      float* Cs = (float*)(smem + OFF_C1);
      int row = tid >> 1, j0 = (tid & 1) * 4;
      union { u16 h[4]; u64 qv; } pk;
#pragma unroll
      for (int i = 0; i < 4; i++) {
        int j = j0 + i;
        float vi = Ds[row * 33 + 0 + j]  + bs[0 + j];
        float vf = Ds[row * 33 + 8 + j]  + bs[8 + j];
        float vo = Ds[row * 33 + 16 + j] + bs[16 + j];
        float vc = Ds[row * 33 + 24 + j] + bs[24 + j];
        float I = sigm(vi), F = sigm(vf), O = sigm(vo), Ct = tanh_(vc);
        float Cn = F * Cs[row * 8 + j] + I * Ct;
        Cs[row * 8 + j] = Cn;
        pk.h[i] = f2bf(O * tanh_(Cn));
      }
      st8_llc(H1b + (size_t)(g * 64 + row) * HID_ + c * 8 + j0, pk.qv);
    }
  }

  // ---- all-groups done (heavy: acquire-inv), then final GEMM with cached loads ----
  donebar(dn, bi);
  if (bi < 250) {
    const int n0 = bi * 128;
    u16* Wf = (u16*)smem;   // reuse weight LDS: [16 kb][8 nt][64 lane][8]
    for (int idx = tid; idx < 512 * 128; idx += NTHR) {
      int k = idx >> 7, nn2 = idx & 127;
      int nt = nn2 >> 4, rr = nn2 & 15;
      int kb = k >> 5, q2 = (k >> 3) & 3, e = k & 7;
      Wf[((size_t)(kb * 8 + nt) * 64 + q2 * 16 + rr) * 8 + e] =
          f2bf(p.Whq[(size_t)k * NCLS + n0 + nn2]);
    }
    float* bqs = (float*)(smem + OFF_C);
    if (tid < 128) bqs[tid] = p.bq[n0 + tid];
    __syncthreads();
    const int r2 = lane & 15, q2 = lane >> 4;
    for (int mt = 0; mt < 4; mt++) {
      int rowb = mt * 64 + w * 16;
      const u16* arow = H1b + (size_t)(rowb + r2) * HID_;
      f32x4 acc[8];
#pragma unroll
      for (int nt = 0; nt < 8; nt++) acc[nt] = (f32x4){0.f, 0.f, 0.f, 0.f};
      for (int kb = 0; kb < 16; kb++) {
        s16x8 a = *(const s16x8*)(arow + kb * 32 + q2 * 8);
#pragma unroll
        for (int nt = 0; nt < 8; nt++) {
          s16x8 b = *(const s16x8*)((const u16*)Wf + ((size_t)(kb * 8 + nt) * 64 + lane) * 8);
          acc[nt] = mfma16(a, b, acc[nt]);
        }
      }
#pragma unroll
      for (int nt = 0; nt < 8; nt++)
#pragma unroll
        for (int i = 0; i < 4; i++)
          p.out[(size_t)(rowb + q2 * 4 + i) * NCLS + n0 + nt * 16 + r2] =
              acc[nt][i] + bqs[nt * 16 + r2];
    }
  }
}

extern "C" void kernel_launch(void* const* d_in, const int* in_sizes, int n_in,
                              void* d_out, int out_size, void* d_ws, size_t ws_size,
                              hipStream_t stream) {
  (void)in_sizes; (void)n_in; (void)out_size; (void)ws_size;
  Params p;
  p.X   = (const int*)d_in[0];
  p.Hin = (const float*)d_in[1];
  p.Cin = (const float*)d_in[2];
  p.E   = (const float*)d_in[3];
  for (int gidx = 0; gidx < 4; gidx++) {   // gate order i,f,o,c
    int base = 4 + gidx * 6;
    p.Wx[gidx]  = (const float*)d_in[base + 0];
    p.Wh[gidx]  = (const float*)d_in[base + 1];
    p.bg[gidx]  = (const float*)d_in[base + 2];
    p.Wx1[gidx] = (const float*)d_in[base + 3];
    p.Wh1[gidx] = (const float*)d_in[base + 4];
    p.bg1[gidx] = (const float*)d_in[base + 5];
  }
  p.Wxh = (const float*)d_in[28];
  p.Whh = (const float*)d_in[29];
  p.bh  = (const float*)d_in[30];
  p.Whq = (const float*)d_in[31];
  p.bq  = (const float*)d_in[32];
  p.out = (float*)d_out;
  p.ws  = (char*)d_ws;

  hipFuncSetAttribute(reinterpret_cast<const void*>(lstm_pers),
                      hipFuncAttributeMaxDynamicSharedMemorySize, SMEM_BYTES);
  lstm_pers<<<dim3(NWG), dim3(NTHR), SMEM_BYTES, stream>>>(p);
}

// Round 5
// 3604.837 us; speedup vs baseline: 2.0518x; 2.0518x over previous
//
#include <hip/hip_runtime.h>
#include <cstdint>
#include <cstddef>

typedef unsigned short u16;
typedef unsigned long long u64;
typedef __attribute__((ext_vector_type(8))) short s16x8;
typedef __attribute__((ext_vector_type(4))) float f32x4;
typedef __attribute__((ext_vector_type(4))) unsigned short u16x4;

#define AGENT __HIP_MEMORY_SCOPE_AGENT

namespace {
constexpr int NWG  = 256;
constexpr int NTHR = 256;
constexpr int Bb   = 256;   // batch
constexpr int Tt   = 256;   // timesteps
constexpr int EMB_ = 256;
constexpr int HID_ = 512;
constexpr int NCLS = 32000;

// ---- LDS layout (bytes). B-operands stored in MFMA lane order:
//      elem addr = ((kb*NT + n)*64 + lane)*8 + e  -> ds_read_b128 lane-linear, 0 conflicts
constexpr int OFF_W1  = 0;        // cell1 [24 kb][2 n][64 lane][8] = 49152 B
constexpr int OFF_W3  = 49152;    // cell2, same shape
constexpr int OFF_W2  = 98304;    // mix   [32 kb][1 n][64][8]     = 32768 B
constexpr int OFF_DS  = 131072;   // cell2 gate scratch [64][33] f32 = 8448 B
constexpr int OFF_DS1 = 139520;   // cell1 gate scratch [64][33] f32 = 8448 B
constexpr int OFF_DSM = 147968;   // mix per-wave transpose 2 x [16][17] f32 = 2176 B
constexpr int OFF_C   = 150144;   // cell1 C state [64][8] f32 (bq reuse in final)
constexpr int OFF_C1  = 152192;   // cell2 C state
constexpr int OFF_B1  = 154240;
constexpr int OFF_B3  = 154368;
constexpr int OFF_B2  = 154496;
constexpr int SMEM_BYTES = 154560;            // 1 WG/CU

// ---- workspace layout (bytes) ----
constexpr size_t WS_FL   = 0;                          // 256 WGs x 128 B = 32 KB
constexpr size_t WS_DONE = 32768;                      // 256 int done flags (one-time)
constexpr size_t WS_HB0  = 33792;                      // H parity buffers [B][512] bf16
constexpr size_t WS_HB1  = WS_HB0 + (size_t)Bb * HID_ * 2;
constexpr size_t WS_H1   = WS_HB1 + (size_t)Bb * HID_ * 2;   // H1 state
constexpr size_t WS_HM   = WS_H1 + (size_t)Bb * HID_ * 2;    // H1mix
constexpr size_t WS_XE   = WS_HM + (size_t)Bb * HID_ * 2;    // Xe [T][B][EMB] bf16
}  // namespace

struct Params {
  const int* X; const float* Hin; const float* Cin; const float* E;
  const float* Wx[4];  const float* Wh[4];  const float* bg[4];   // cell 1 (i,f,o,c)
  const float* Wx1[4]; const float* Wh1[4]; const float* bg1[4];  // cell 2
  const float* Wxh; const float* Whh; const float* bh;
  const float* Whq; const float* bq;
  float* out; char* ws;
};

__device__ __forceinline__ u16 f2bf(float f) {
  union { float f; unsigned u; } v; v.f = f;
  unsigned r = v.u + 0x7FFFu + ((v.u >> 16) & 1u);
  return (u16)(r >> 16);
}
__device__ __forceinline__ float sigm(float x) { return 1.f / (1.f + __expf(-x)); }
__device__ __forceinline__ float tanh_(float x) {
  x = fminf(fmaxf(x, -10.f), 10.f);
  float e = __expf(-2.f * x);
  return (1.f - e) / (1.f + e);
}
__device__ __forceinline__ f32x4 mfma16(s16x8 a, s16x8 b, f32x4 c) {
  return __builtin_amdgcn_mfma_f32_16x16x32_bf16(a, b, c, 0, 0, 0);
}

// ---- producer side: LLC-coherent bypass stores (relaxed agent atomics).
__device__ __forceinline__ void st8_llc(u16* p2, u64 v) {
  __hip_atomic_store((u64*)p2, v, __ATOMIC_RELAXED, AGENT);
}

// ---- consumer side: 16B LLC-coherent bypass loads (sc0 sc1 = bypass L1/L2,
// serviced at the memory-side Infinity Cache). Full-line coalescing: 4 lanes
// x 16B = one 64B fabric txn (vs 2x8B atomic loads = 2 half-line txns).
// "memory" clobber keeps them ordered vs the barrier's atomic ops.
#define LD16A(d, b, off)                                                      \
  asm volatile("global_load_dwordx4 %0, %1, off offset:" #off " sc0 sc1"      \
               : "=&v"(d) : "v"(b) : "memory")

__device__ __forceinline__ void ld_h16(s16x8* d, const u16* b) {
  LD16A(d[0],  b, 0);   LD16A(d[1],  b, 64);  LD16A(d[2],  b, 128);
  LD16A(d[3],  b, 192); LD16A(d[4],  b, 256); LD16A(d[5],  b, 320);
  LD16A(d[6],  b, 384); LD16A(d[7],  b, 448); LD16A(d[8],  b, 512);
  LD16A(d[9],  b, 576); LD16A(d[10], b, 640); LD16A(d[11], b, 704);
  LD16A(d[12], b, 768); LD16A(d[13], b, 832); LD16A(d[14], b, 896);
  LD16A(d[15], b, 960);
}
// Drain asm loads; sched_barrier(0) stops MFMAs hoisting above the waitcnt
// (compiler treats asm outputs as immediately available -- rule #18).
__device__ __forceinline__ void waitld() {
  asm volatile("s_waitcnt vmcnt(0)" ::: "memory");
  __builtin_amdgcn_sched_barrier(0);
}

// Split barrier: arrive (after our stores drained by __syncthreads' vmcnt(0)) /
// waitbar (poll all 64 flags). Light: no cache maintenance (all exchange data
// is LLC-coherent bypass traffic).
__device__ __forceinline__ void arrive(int* fl, int slot, int ph) {
  __syncthreads();
  if (threadIdx.x == 0)
    __hip_atomic_store(&fl[slot * 32], ph, __ATOMIC_RELAXED, AGENT);
}
__device__ __forceinline__ void waitbar(int* fl, int ph) {
  if (threadIdx.x < 64) {
    for (;;) {
      int v = __hip_atomic_load(&fl[threadIdx.x * 32], __ATOMIC_RELAXED, AGENT);
      if (!__any(v < ph)) break;
      __builtin_amdgcn_s_sleep(1);
    }
  }
  __syncthreads();
  __builtin_amdgcn_fence(__ATOMIC_ACQUIRE, "workgroup");  // compiler/order barrier, cheap
}

// Heavy barrier (release store + agent acquire fence -> wbl2/inv). Used ONCE
// after init (publishes normal-stored Xe/H-init).
__device__ __forceinline__ void groupbar_heavy(int* fl, int slot, int ph) {
  __syncthreads();
  if (threadIdx.x == 0)
    __hip_atomic_store(&fl[slot * 32], ph, __ATOMIC_RELEASE, AGENT);
  if (threadIdx.x < 64) {
    for (;;) {
      int v = __hip_atomic_load(&fl[threadIdx.x * 32], __ATOMIC_RELAXED, AGENT);
      if (!__any(v < ph)) break;
      __builtin_amdgcn_s_sleep(1);
    }
  }
  __syncthreads();
  __builtin_amdgcn_fence(__ATOMIC_ACQUIRE, "agent");
}

// One-time all-grid done wait (before the final GEMM). Heavy on purpose: its
// acquire-inv lets the final GEMM use normal cached loads on H1b.
__device__ __forceinline__ void donebar(int* dn, int bi) {
  __syncthreads();
  if (threadIdx.x == 0)
    __hip_atomic_store(&dn[bi], 1, __ATOMIC_RELEASE, AGENT);
  for (;;) {
    int v = __hip_atomic_load(&dn[threadIdx.x], __ATOMIC_RELAXED, AGENT);
    if (!__any(v < 1)) break;
    __builtin_amdgcn_s_sleep(1);
  }
  __syncthreads();
  __builtin_amdgcn_fence(__ATOMIC_ACQUIRE, "agent");
}

// Single-cell phase (prologue cell1(0) only; 4 waves, full syncthreads handoff).
__device__ __forceinline__ void cell_phase(char* smem, int offW, int offB, int offC,
                                           const u16* Xt, const u16* Hrec, u16* Hdst,
                                           int g, int c, int w, int lane, int tid) {
  const int r = lane & 15, q = lane >> 4;
  const int row0 = w * 16;
  const u16* xrow = Xt + (size_t)(g * 64 + row0 + r) * EMB_;
  const u16* hrow = Hrec + (size_t)(g * 64 + row0 + r) * HID_;
  const u16* wb = (const u16*)(smem + offW) + lane * 8;
  f32x4 acc0 = {0.f, 0.f, 0.f, 0.f}, acc1 = {0.f, 0.f, 0.f, 0.f};
#pragma unroll
  for (int kb = 0; kb < 8; kb++) {                    // x_t part of K (256)
    s16x8 a  = *(const s16x8*)(xrow + kb * 32 + q * 8);
    s16x8 b0 = *(const s16x8*)(wb + (size_t)(kb * 2 + 0) * 512);
    s16x8 b1 = *(const s16x8*)(wb + (size_t)(kb * 2 + 1) * 512);
    acc0 = mfma16(a, b0, acc0);
    acc1 = mfma16(a, b1, acc1);
  }
  s16x8 ha[16];
  ld_h16(ha, hrow + q * 8);
  waitld();
#pragma unroll
  for (int kb = 0; kb < 16; kb++) {                   // recurrent part of K (512)
    s16x8 b0 = *(const s16x8*)(wb + (size_t)((kb + 8) * 2 + 0) * 512);
    s16x8 b1 = *(const s16x8*)(wb + (size_t)((kb + 8) * 2 + 1) * 512);
    acc0 = mfma16(ha[kb], b0, acc0);
    acc1 = mfma16(ha[kb], b1, acc1);
  }
  float* Ds = (float*)(smem + OFF_DS);
#pragma unroll
  for (int i = 0; i < 4; i++) {
    Ds[(row0 + q * 4 + i) * 33 + r]      = acc0[i];
    Ds[(row0 + q * 4 + i) * 33 + 16 + r] = acc1[i];
  }
  __syncthreads();
  const float* bs = (const float*)(smem + offB);
  float* Cs = (float*)(smem + offC);
  if (tid < 128) {
    int row = tid >> 1, j0 = (tid & 1) * 4;
    union { u16 h[4]; u64 qv; } pk;
#pragma unroll
    for (int i = 0; i < 4; i++) {
      int j = j0 + i;
      float vi = Ds[row * 33 + 0 + j]  + bs[0 + j];
      float vf = Ds[row * 33 + 8 + j]  + bs[8 + j];
      float vo = Ds[row * 33 + 16 + j] + bs[16 + j];
      float vc = Ds[row * 33 + 24 + j] + bs[24 + j];
      float I = sigm(vi), F = sigm(vf), O = sigm(vo), Ct = tanh_(vc);
      float Cn = F * Cs[row * 8 + j] + I * Ct;
      Cs[row * 8 + j] = Cn;
      pk.h[i] = f2bf(O * tanh_(Cn));
    }
    st8_llc(Hdst + (size_t)(g * 64 + row) * HID_ + c * 8 + j0, pk.qv);
  }
}

// cell1 on waves 2-3 only: full gate GEMM + elementwise + H-store, no barrier.
// Wave wv ({0,1} = tid>>6 - 2) owns rows wv*32..+31; scratch handoff is
// intra-wave (lgkmcnt only). Runs entirely PRE-wait inside phase B.
__device__ __forceinline__ void cell1_w23(char* smem, const u16* Xt, const u16* Hrec,
                                          u16* Hdst, int g, int c, int lane, int tid) {
  const int wv = (tid >> 6) - 2;
  const int r = lane & 15, q = lane >> 4;
  const u16* wb1 = (const u16*)(smem + OFF_W1) + lane * 8;
  float* D1 = (float*)(smem + OFF_DS1);
#pragma unroll
  for (int blk = 0; blk < 2; blk++) {
    const int rb = wv * 32 + blk * 16;
    const u16* xrow = Xt + (size_t)(g * 64 + rb + r) * EMB_;
    const u16* hrow = Hrec + (size_t)(g * 64 + rb + r) * HID_;
    s16x8 xa[8];
#pragma unroll
    for (int kb = 0; kb < 8; kb++) xa[kb] = *(const s16x8*)(xrow + kb * 32 + q * 8);
    s16x8 hh[16];
    ld_h16(hh, hrow + q * 8);
    f32x4 a0 = {0.f, 0.f, 0.f, 0.f}, a1 = {0.f, 0.f, 0.f, 0.f};
#pragma unroll
    for (int kb = 0; kb < 8; kb++) {
      a0 = mfma16(xa[kb], *(const s16x8*)(wb1 + (size_t)(kb * 2 + 0) * 512), a0);
      a1 = mfma16(xa[kb], *(const s16x8*)(wb1 + (size_t)(kb * 2 + 1) * 512), a1);
    }
    waitld();
#pragma unroll
    for (int kb = 0; kb < 16; kb++) {
      a0 = mfma16(hh[kb], *(const s16x8*)(wb1 + (size_t)((kb + 8) * 2 + 0) * 512), a0);
      a1 = mfma16(hh[kb], *(const s16x8*)(wb1 + (size_t)((kb + 8) * 2 + 1) * 512), a1);
    }
#pragma unroll
    for (int i = 0; i < 4; i++) {
      D1[(rb + q * 4 + i) * 33 + r]      = a0[i];
      D1[(rb + q * 4 + i) * 33 + 16 + r] = a1[i];
    }
  }
  // elementwise: wave wv reads rows wv*32..+31, which it wrote (intra-wave)
  const float* bs = (const float*)(smem + OFF_B1);
  float* Cs = (float*)(smem + OFF_C);
  int t2 = tid - 128;
  int row = t2 >> 1, j0 = (t2 & 1) * 4;
  union { u16 h[4]; u64 qv; } pk;
#pragma unroll
  for (int i = 0; i < 4; i++) {
    int j = j0 + i;
    float vi = D1[row * 33 + 0 + j]  + bs[0 + j];
    float vf = D1[row * 33 + 8 + j]  + bs[8 + j];
    float vo = D1[row * 33 + 16 + j] + bs[16 + j];
    float vc = D1[row * 33 + 24 + j] + bs[24 + j];
    float I = sigm(vi), F = sigm(vf), O = sigm(vo), Ct = tanh_(vc);
    float Cn = F * Cs[row * 8 + j] + I * Ct;
    Cs[row * 8 + j] = Cn;
    pk.h[i] = f2bf(O * tanh_(Cn));
  }
  st8_llc(Hdst + (size_t)(g * 64 + row) * HID_ + c * 8 + j0, pk.qv);
}

// mix part 1 (pre-wait): acc = H(t+1) @ W_xh  (waves 0-1 only)
__device__ __forceinline__ f32x4 mix_part1(char* smem, const u16* Hnew, int g, int c,
                                           int w, int lane) {
  const int r = lane & 15, q = lane >> 4;
  int rbase = g * 64 + (c & 1) * 32 + w * 16 + r;
  const u16* h0 = Hnew + (size_t)rbase * HID_;
  const u16* wb = (const u16*)(smem + OFF_W2) + lane * 8;
  s16x8 ha[16];
  ld_h16(ha, h0 + q * 8);
  waitld();
  f32x4 acc = {0.f, 0.f, 0.f, 0.f};
#pragma unroll
  for (int kb = 0; kb < 16; kb++)
    acc = mfma16(ha[kb], *(const s16x8*)(wb + (size_t)kb * 512), acc);
  return acc;
}

// mix part 2 (post-wait): acc += H1(t) @ W_hh; sigmoid; store H1m.
// Output transpose via per-wave private LDS (intra-wave, no barrier).
__device__ __forceinline__ void mix_part2(char* smem, f32x4 acc, const u16* H1old,
                                          u16* H1m, int g, int c, int w, int lane) {
  const int r = lane & 15, q = lane >> 4;
  int rbase = g * 64 + (c & 1) * 32 + w * 16 + r;
  const u16* h1 = H1old + (size_t)rbase * HID_;
  const u16* wb = (const u16*)(smem + OFF_W2) + lane * 8;
  s16x8 hb[16];
  ld_h16(hb, h1 + q * 8);
  waitld();
#pragma unroll
  for (int kb = 0; kb < 16; kb++)
    acc = mfma16(hb[kb], *(const s16x8*)(wb + (size_t)(16 + kb) * 512), acc);
  float* Dm = (float*)(smem + OFF_DSM) + (size_t)w * 16 * 17;
#pragma unroll
  for (int i = 0; i < 4; i++) Dm[(q * 4 + i) * 17 + r] = acc[i];
  const float* b2 = (const float*)(smem + OFF_B2);
  int row2 = lane >> 2, j0 = (lane & 3) * 4;
  union { u16 h[4]; u64 qv; } pk;
#pragma unroll
  for (int i = 0; i < 4; i++)
    pk.h[i] = f2bf(sigm(Dm[row2 * 17 + j0 + i] + b2[j0 + i]));
  st8_llc(H1m + (size_t)(g * 64 + (c & 1) * 32 + w * 16 + row2) * HID_ + (c >> 1) * 16 + j0,
          pk.qv);
}

__global__ __launch_bounds__(NTHR, 1) void lstm_pers(Params p) {
  extern __shared__ char smem[];
  const int tid = threadIdx.x;
  const int bi = blockIdx.x;
  const int w = tid >> 6, lane = tid & 63;
  const int g = bi >> 6, c = bi & 63;
  const int r = lane & 15, q = lane >> 4;

  int* fl = (int*)(p.ws + WS_FL) + g * 64 * 32;   // padded: one line per WG
  int* dn = (int*)(p.ws + WS_DONE);
  u16* Hb0 = (u16*)(p.ws + WS_HB0);
  u16* Hb1 = (u16*)(p.ws + WS_HB1);
  u16* H1b = (u16*)(p.ws + WS_H1);
  u16* H1m = (u16*)(p.ws + WS_HM);
  u16* Xe  = (u16*)(p.ws + WS_XE);

  // ---- one-time init: weights -> LDS (bf16, MFMA lane-order swizzle) ----
  {
    u16* w1 = (u16*)(smem + OFF_W1);
    u16* w3 = (u16*)(smem + OFF_W3);
    int gate = tid >> 6, kk8 = (tid >> 3) & 7, j = tid & 7;
    int cc = gate * 8 + j;          // col 0..31 (i0..7,f0..7,o0..7,c0..7)
    int n = cc >> 4, rr = cc & 15;
    int hid = c * 8 + j;
    for (int kk = kk8; kk < 768; kk += 8) {
      int kb = kk >> 5, q2 = (kk >> 3) & 3, e = kk & 7;
      size_t dst = ((size_t)(kb * 2 + n) * 64 + q2 * 16 + rr) * 8 + e;
      float s1 = (kk < 256) ? p.Wx[gate][(size_t)kk * HID_ + hid]
                            : p.Wh[gate][(size_t)(kk - 256) * HID_ + hid];
      float s3 = (kk < 256) ? p.Wx1[gate][(size_t)kk * HID_ + hid]
                            : p.Wh1[gate][(size_t)(kk - 256) * HID_ + hid];
      w1[dst] = f2bf(s1);
      w3[dst] = f2bf(s3);
    }
    {  // mix weights: every WG holds cols (c>>1)*16..+15 (pairs share)
      u16* w2 = (u16*)(smem + OFF_W2);
      int kk16 = tid >> 4, j2 = tid & 15;
      int hid2 = (c >> 1) * 16 + j2;
      for (int kk = kk16; kk < 1024; kk += 16) {
        int kb = kk >> 5, q2 = (kk >> 3) & 3, e = kk & 7;
        size_t dst = ((size_t)kb * 64 + q2 * 16 + j2) * 8 + e;
        float s = (kk < 512) ? p.Wxh[(size_t)kk * HID_ + hid2]
                             : p.Whh[(size_t)(kk - 512) * HID_ + hid2];
        w2[dst] = f2bf(s);
      }
      if (tid < 16) ((float*)(smem + OFF_B2))[tid] = p.bh[(c >> 1) * 16 + tid];
    }
    if (tid < 32) {
      int gt = tid >> 3, jj = tid & 7;
      ((float*)(smem + OFF_B1))[tid] = p.bg[gt][c * 8 + jj];
      ((float*)(smem + OFF_B3))[tid] = p.bg1[gt][c * 8 + jj];
    }
    // C / C1 state (fp32, LDS-resident, WG-local forever)
    float* Cs = (float*)(smem + OFF_C);
    float* C1s = (float*)(smem + OFF_C1);
    for (int it = 0; it < 2; it++) {
      int idx = tid + it * 256;
      int row = idx >> 3, j8 = idx & 7;
      float v = p.Cin[(size_t)(g * 64 + row) * HID_ + c * 8 + j8];
      Cs[row * 8 + j8] = v;
      C1s[row * 8 + j8] = v;
    }
  }
  // H / H1 state init (bf16 in ws, normal stores -> published by heavy barrier)
  // Convention: H(t) lives in Hb[t&1]; H(-1)=Hin in Hb1.
  for (int it = 0; it < 2; it++) {
    int idx = bi * 512 + tid + it * 256;
    u16 hv = f2bf(p.Hin[idx]);
    Hb1[idx] = hv;
    H1b[idx] = hv;
  }
  // Embedding gather, group-local: WG (g,c) fills Xe[t=4c..4c+3][g*64..+63][:]
  for (int tt = 0; tt < 4; tt++) {
    int t0 = c * 4 + tt;
    for (int pp = 0; pp < 16; pp++) {
      int b = g * 64 + w * 16 + pp;
      int tok = p.X[(size_t)b * Tt + t0];
      const float4* er = (const float4*)(p.E + (size_t)tok * EMB_);
      float4 v = er[lane];
      u16x4 u; u.x = f2bf(v.x); u.y = f2bf(v.y); u.z = f2bf(v.z); u.w = f2bf(v.w);
      *(u16x4*)(Xe + ((size_t)t0 * Bb + b) * EMB_ + lane * 4) = u;
    }
  }
  int ph = 0;
  groupbar_heavy(fl, c, ++ph);   // ph=1: publish init data

  // ---- P0: cell1(0): H(-1)=Hb1 -> H(0)=Hb0 ----
  cell_phase(smem, OFF_W1, OFF_B1, OFF_C, Xe, Hb1, Hb0, g, c, w, lane, tid);
  arrive(fl, c, ++ph);           // ph=2

  // ---- P1: mix(0) [waves 0-1] + cell1(1) [waves 2-3] ----
  waitbar(fl, ph);
  if (w < 2) {
    f32x4 macc = mix_part1(smem, Hb0, g, c, w, lane);   // H(0) @ W_xh
    mix_part2(smem, macc, H1b, H1m, g, c, w, lane);     // + H1(-1) @ W_hh
  } else {
    cell1_w23(smem, Xe + (size_t)1 * Bb * EMB_, Hb0, Hb1, g, c, lane, tid);  // H(0)->H(1)
  }
  arrive(fl, c, ++ph);           // ph=3

  // ---- steady state: 2 thin phases per timestep ----
  for (int t = 0; t < Tt - 1; t++) {
    const u16* Xt = Xe + (size_t)t * Bb * EMB_;
    // ---------- Phase A_t: cell2(t) ----------
    {
      const u16* wb3 = (const u16*)(smem + OFF_W3) + lane * 8;
      const u16* xrow = Xt + (size_t)(g * 64 + w * 16 + r) * EMB_;
      f32x4 acc0 = {0.f, 0.f, 0.f, 0.f}, acc1 = {0.f, 0.f, 0.f, 0.f};
      s16x8 xa[8];
#pragma unroll
      for (int kb = 0; kb < 8; kb++) xa[kb] = *(const s16x8*)(xrow + kb * 32 + q * 8);
#pragma unroll
      for (int kb = 0; kb < 8; kb++) {     // x-part pre-wait
        acc0 = mfma16(xa[kb], *(const s16x8*)(wb3 + (size_t)(kb * 2 + 0) * 512), acc0);
        acc1 = mfma16(xa[kb], *(const s16x8*)(wb3 + (size_t)(kb * 2 + 1) * 512), acc1);
      }
      waitbar(fl, ph);                     // need H1m(t) from B_{t-1}
      const u16* hrow = H1m + (size_t)(g * 64 + w * 16 + r) * HID_;
      s16x8 ha[16];
      ld_h16(ha, hrow + q * 8);
      waitld();
#pragma unroll
      for (int kb = 0; kb < 16; kb++) {
        acc0 = mfma16(ha[kb], *(const s16x8*)(wb3 + (size_t)((kb + 8) * 2 + 0) * 512), acc0);
        acc1 = mfma16(ha[kb], *(const s16x8*)(wb3 + (size_t)((kb + 8) * 2 + 1) * 512), acc1);
      }
      float* Ds = (float*)(smem + OFF_DS);
#pragma unroll
      for (int i = 0; i < 4; i++) {
        Ds[(w * 16 + q * 4 + i) * 33 + r]      = acc0[i];
        Ds[(w * 16 + q * 4 + i) * 33 + 16 + r] = acc1[i];
      }
      __syncthreads();
      if (tid < 128) {
        const float* bs = (const float*)(smem + OFF_B3);
        float* Cs = (float*)(smem + OFF_C1);
        int row = tid >> 1, j0 = (tid & 1) * 4;
        union { u16 h[4]; u64 qv; } pk;
#pragma unroll
        for (int i = 0; i < 4; i++) {
          int j = j0 + i;
          float vi = Ds[row * 33 + 0 + j]  + bs[0 + j];
          float vf = Ds[row * 33 + 8 + j]  + bs[8 + j];
          float vo = Ds[row * 33 + 16 + j] + bs[16 + j];
          float vc = Ds[row * 33 + 24 + j] + bs[24 + j];
          float I = sigm(vi), F = sigm(vf), O = sigm(vo), Ct = tanh_(vc);
          float Cn = F * Cs[row * 8 + j] + I * Ct;
          Cs[row * 8 + j] = Cn;
          pk.h[i] = f2bf(O * tanh_(Cn));
        }
        st8_llc(H1b + (size_t)(g * 64 + row) * HID_ + c * 8 + j0, pk.qv);
      }
      arrive(fl, c, ++ph);
    }
    // ---------- Phase B_t: mix(t+1) [w 0-1] + cell1(t+2) [w 2-3, pre-wait] ----------
    {
      const u16* Hnew = (t & 1) ? Hb0 : Hb1;   // H(t+1)
      u16* Hdst1      = (t & 1) ? Hb1 : Hb0;   // H(t+2)
      f32x4 macc = {0.f, 0.f, 0.f, 0.f};
      if (w < 2) {
        macc = mix_part1(smem, Hnew, g, c, w, lane);        // pre-wait half
      } else if (t + 2 < Tt) {
        cell1_w23(smem, Xe + (size_t)(t + 2) * Bb * EMB_, Hnew, Hdst1, g, c, lane, tid);
      }
      waitbar(fl, ph);                       // need H1(t) from A_t
      if (w < 2) mix_part2(smem, macc, H1b, H1m, g, c, w, lane);
      arrive(fl, c, ++ph);
    }
  }

  // ---- epilogue: cell2(255) ----
  {
    const u16* Xt = Xe + (size_t)(Tt - 1) * Bb * EMB_;
    const u16* wb3 = (const u16*)(smem + OFF_W3) + lane * 8;
    const u16* xrow = Xt + (size_t)(g * 64 + w * 16 + r) * EMB_;
    f32x4 acc0 = {0.f, 0.f, 0.f, 0.f}, acc1 = {0.f, 0.f, 0.f, 0.f};
    s16x8 xa[8];
#pragma unroll
    for (int kb = 0; kb < 8; kb++) xa[kb] = *(const s16x8*)(xrow + kb * 32 + q * 8);
#pragma unroll
    for (int kb = 0; kb < 8; kb++) {
      acc0 = mfma16(xa[kb], *(const s16x8*)(wb3 + (size_t)(kb * 2 + 0) * 512), acc0);
      acc1 = mfma16(xa[kb], *(const s16x8*)(wb3 + (size_t)(kb * 2 + 1) * 512), acc1);
    }
    waitbar(fl, ph);                         // mix(255) from B_254
    const u16* hrow = H1m + (size_t)(g * 64 + w * 16 + r) * HID_;
    s16x8 ha[16];
    ld_h16(ha, hrow + q * 8);
    waitld();
#pragma unroll
    for (int kb = 0; kb < 16; kb++) {
      acc0 = mfma16(ha[kb], *(const s16x8*)(wb3 + (size_t)((kb + 8) * 2 + 0) * 512), acc0);
      acc1 = mfma16(ha[kb], *(const s16x8*)(wb3 + (size_t)((kb + 8) * 2 + 1) * 512), acc1);
    }
    float* Ds = (float*)(smem + OFF_DS);
#pragma unroll
    for (int i = 0; i < 4; i++) {
      Ds[(w * 16 + q * 4 + i) * 33 + r]      = acc0[i];
      Ds[(w * 16 + q * 4 + i) * 33 + 16 + r] = acc1[i];
    }
    __syncthreads();
    if (tid < 128) {
      const float* bs = (const float*)(smem + OFF_B3);
      float* Cs = (float*)(smem + OFF_C1);
      int row = tid >> 1, j0 = (tid & 1) * 4;
      union { u16 h[4]; u64 qv; } pk;
#pragma unroll
      for (int i = 0; i < 4; i++) {
        int j = j0 + i;
        float vi = Ds[row * 33 + 0 + j]  + bs[0 + j];
        float vf = Ds[row * 33 + 8 + j]  + bs[8 + j];
        float vo = Ds[row * 33 + 16 + j] + bs[16 + j];
        float vc = Ds[row * 33 + 24 + j] + bs[24 + j];
        float I = sigm(vi), F = sigm(vf), O = sigm(vo), Ct = tanh_(vc);
        float Cn = F * Cs[row * 8 + j] + I * Ct;
        Cs[row * 8 + j] = Cn;
        pk.h[i] = f2bf(O * tanh_(Cn));
      }
      st8_llc(H1b + (size_t)(g * 64 + row) * HID_ + c * 8 + j0, pk.qv);
    }
  }

  // ---- all-groups done (heavy: acquire-inv), then final GEMM with cached loads ----
  donebar(dn, bi);
  if (bi < 250) {
    const int n0 = bi * 128;
    u16* Wf = (u16*)smem;   // reuse weight LDS: [16 kb][8 nt][64 lane][8]
    for (int idx = tid; idx < 512 * 128; idx += NTHR) {
      int k = idx >> 7, nn2 = idx & 127;
      int nt = nn2 >> 4, rr = nn2 & 15;
      int kb = k >> 5, q2 = (k >> 3) & 3, e = k & 7;
      Wf[((size_t)(kb * 8 + nt) * 64 + q2 * 16 + rr) * 8 + e] =
          f2bf(p.Whq[(size_t)k * NCLS + n0 + nn2]);
    }
    float* bqs = (float*)(smem + OFF_C);
    if (tid < 128) bqs[tid] = p.bq[n0 + tid];
    __syncthreads();
    const int r2 = lane & 15, q2 = lane >> 4;
    for (int mt = 0; mt < 4; mt++) {
      int rowb = mt * 64 + w * 16;
      const u16* arow = H1b + (size_t)(rowb + r2) * HID_;
      f32x4 acc[8];
#pragma unroll
      for (int nt = 0; nt < 8; nt++) acc[nt] = (f32x4){0.f, 0.f, 0.f, 0.f};
      for (int kb = 0; kb < 16; kb++) {
        s16x8 a = *(const s16x8*)(arow + kb * 32 + q2 * 8);
#pragma unroll
        for (int nt = 0; nt < 8; nt++) {
          s16x8 b = *(const s16x8*)((const u16*)Wf + ((size_t)(kb * 8 + nt) * 64 + lane) * 8);
          acc[nt] = mfma16(a, b, acc[nt]);
        }
      }
#pragma unroll
      for (int nt = 0; nt < 8; nt++)
#pragma unroll
        for (int i = 0; i < 4; i++)
          p.out[(size_t)(rowb + q2 * 4 + i) * NCLS + n0 + nt * 16 + r2] =
              acc[nt][i] + bqs[nt * 16 + r2];
    }
  }
}

extern "C" void kernel_launch(void* const* d_in, const int* in_sizes, int n_in,
                              void* d_out, int out_size, void* d_ws, size_t ws_size,
                              hipStream_t stream) {
  (void)in_sizes; (void)n_in; (void)out_size; (void)ws_size;
  Params p;
  p.X   = (const int*)d_in[0];
  p.Hin = (const float*)d_in[1];
  p.Cin = (const float*)d_in[2];
  p.E   = (const float*)d_in[3];
  for (int gidx = 0; gidx < 4; gidx++) {   // gate order i,f,o,c
    int base = 4 + gidx * 6;
    p.Wx[gidx]  = (const float*)d_in[base + 0];
    p.Wh[gidx]  = (const float*)d_in[base + 1];
    p.bg[gidx]  = (const float*)d_in[base + 2];
    p.Wx1[gidx] = (const float*)d_in[base + 3];
    p.Wh1[gidx] = (const float*)d_in[base + 4];
    p.bg1[gidx] = (const float*)d_in[base + 5];
  }
  p.Wxh = (const float*)d_in[28];
  p.Whh = (const float*)d_in[29];
  p.bh  = (const float*)d_in[30];
  p.Whq = (const float*)d_in[31];
  p.bq  = (const float*)d_in[32];
  p.out = (float*)d_out;
  p.ws  = (char*)d_ws;

  hipFuncSetAttribute(reinterpret_cast<const void*>(lstm_pers),
                      hipFuncAttributeMaxDynamicSharedMemorySize, SMEM_BYTES);
  lstm_pers<<<dim3(NWG), dim3(NTHR), SMEM_BYTES, stream>>>(p);
}

// Round 7
// 3554.026 us; speedup vs baseline: 2.0811x; 1.0143x over previous
//
#include <hip/hip_runtime.h>
#include <cstdint>
#include <cstddef>

typedef unsigned short u16;
typedef unsigned long long u64;
typedef __attribute__((ext_vector_type(8))) short s16x8;
typedef __attribute__((ext_vector_type(4))) float f32x4;
typedef __attribute__((ext_vector_type(4))) unsigned short u16x4;

#define AGENT __HIP_MEMORY_SCOPE_AGENT

namespace {
constexpr int NWG  = 256;
constexpr int NTHR = 256;
constexpr int Bb   = 256;   // batch
constexpr int Tt   = 256;   // timesteps
constexpr int EMB_ = 256;
constexpr int HID_ = 512;
constexpr int NCLS = 32000;

// ---- LDS layout (bytes). B-operands stored in MFMA lane order:
//      elem addr = ((kb*NT + n)*64 + lane)*8 + e  -> ds_read_b128 lane-linear, 0 conflicts
constexpr int OFF_W1  = 0;        // cell1 [24 kb][2 n][64 lane][8] = 49152 B
constexpr int OFF_W3  = 49152;    // cell2, same shape
constexpr int OFF_W2  = 98304;    // mix   [32 kb][1 n][64][8]     = 32768 B
constexpr int OFF_DS  = 131072;   // cell2 gate scratch [64][33] f32 = 8448 B
constexpr int OFF_DS1 = 139520;   // cell1 gate scratch [64][33] f32 = 8448 B
constexpr int OFF_DSM = 147968;   // mix per-wave transpose 2 x [16][17] f32 = 2176 B
constexpr int OFF_C   = 150144;   // cell1 C state [64][8] f32 (bq reuse in final)
constexpr int OFF_C1  = 152192;   // cell2 C state
constexpr int OFF_B1  = 154240;
constexpr int OFF_B3  = 154368;
constexpr int OFF_B2  = 154496;
constexpr int SMEM_BYTES = 154560;            // 1 WG/CU

// ---- workspace layout (bytes) ----
// fl lines: 256 x 128B. dword +0 of each line: heavy-barrier flag (init only;
// store-then-compare -> immune to workspace poison).
// dword +16 (byte +64, separate 64B sector) of lines (g*64 + 0..7): monotonic
// phase counters. RMW on workspace -> MUST be explicitly zeroed during init
// (harness POISONS the workspace, it does not zero it; un-zeroed counters
// deadlock -- rounds 3/6 failure mode).
constexpr size_t WS_FL   = 0;                          // 256 WGs x 128 B = 32 KB
constexpr size_t WS_DONE = 32768;                      // 256 int done flags (one-time)
constexpr size_t WS_HB0  = 33792;                      // H parity buffers [B][512] bf16
constexpr size_t WS_HB1  = WS_HB0 + (size_t)Bb * HID_ * 2;
constexpr size_t WS_H1   = WS_HB1 + (size_t)Bb * HID_ * 2;   // H1 state
constexpr size_t WS_HM   = WS_H1 + (size_t)Bb * HID_ * 2;    // H1mix
constexpr size_t WS_XE   = WS_HM + (size_t)Bb * HID_ * 2;    // Xe [T][B][EMB] bf16
}  // namespace

struct Params {
  const int* X; const float* Hin; const float* Cin; const float* E;
  const float* Wx[4];  const float* Wh[4];  const float* bg[4];   // cell 1 (i,f,o,c)
  const float* Wx1[4]; const float* Wh1[4]; const float* bg1[4];  // cell 2
  const float* Wxh; const float* Whh; const float* bh;
  const float* Whq; const float* bq;
  float* out; char* ws;
};

__device__ __forceinline__ u16 f2bf(float f) {
  union { float f; unsigned u; } v; v.f = f;
  unsigned r = v.u + 0x7FFFu + ((v.u >> 16) & 1u);
  return (u16)(r >> 16);
}
__device__ __forceinline__ float sigm(float x) { return 1.f / (1.f + __expf(-x)); }
__device__ __forceinline__ float tanh_(float x) {
  x = fminf(fmaxf(x, -10.f), 10.f);
  float e = __expf(-2.f * x);
  return (1.f - e) / (1.f + e);
}
__device__ __forceinline__ f32x4 mfma16(s16x8 a, s16x8 b, f32x4 c) {
  return __builtin_amdgcn_mfma_f32_16x16x32_bf16(a, b, c, 0, 0, 0);
}

// ---- producer side: LLC-coherent bypass stores (relaxed agent atomics).
__device__ __forceinline__ void st8_llc(u16* p2, u64 v) {
  __hip_atomic_store((u64*)p2, v, __ATOMIC_RELAXED, AGENT);
}

// ---- consumer side: 16B LLC-coherent bypass loads (sc0 sc1 = bypass L1/L2,
// serviced at the memory-side Infinity Cache). Full-line coalescing: 4 lanes
// x 16B = one 64B fabric txn. "memory" clobber keeps them ordered vs the
// barrier's atomic ops (proven safe in round 5).
#define LD16A(d, b, off)                                                      \
  asm volatile("global_load_dwordx4 %0, %1, off offset:" #off " sc0 sc1"      \
               : "=&v"(d) : "v"(b) : "memory")

__device__ __forceinline__ void ld_h16(s16x8* d, const u16* b) {
  LD16A(d[0],  b, 0);   LD16A(d[1],  b, 64);  LD16A(d[2],  b, 128);
  LD16A(d[3],  b, 192); LD16A(d[4],  b, 256); LD16A(d[5],  b, 320);
  LD16A(d[6],  b, 384); LD16A(d[7],  b, 448); LD16A(d[8],  b, 512);
  LD16A(d[9],  b, 576); LD16A(d[10], b, 640); LD16A(d[11], b, 704);
  LD16A(d[12], b, 768); LD16A(d[13], b, 832); LD16A(d[14], b, 896);
  LD16A(d[15], b, 960);
}
// Drain asm loads; sched_barrier(0) stops MFMAs hoisting above the waitcnt
// (compiler treats asm outputs as immediately available -- rule #18).
__device__ __forceinline__ void waitld() {
  asm volatile("s_waitcnt vmcnt(0)" ::: "memory");
  __builtin_amdgcn_sched_barrier(0);
}

// ---- counter barrier (steady state): arrive = one atomicAdd to sub-counter
// (c&7); wait = 8 lanes poll 8 lines until all == 8*ph. Monotonic, no reset.
// Counters are EXPLICITLY ZEROED in init (workspace is poisoned, not zeroed).
// __syncthreads drains vmcnt so all sc1 data stores are LLC-acked before the
// add is issued -> data visible before the count. 8x less poll traffic than
// the 64-flag poll (8 lanes x 8 lines vs 64 x 64).
__device__ __forceinline__ void arrive_cnt(int* fl, int c) {
  __syncthreads();
  if (threadIdx.x == 0)
    (void)__hip_atomic_fetch_add(&fl[(c & 7) * 32 + 16], 1, __ATOMIC_RELAXED, AGENT);
}
__device__ __forceinline__ void wait_cnt(int* fl, int ph) {
  const int tgt = ph * 8;
  if (threadIdx.x < 8) {
    for (;;) {
      int v = __hip_atomic_load(&fl[threadIdx.x * 32 + 16], __ATOMIC_RELAXED, AGENT);
      if (!__any(v < tgt)) break;
      __builtin_amdgcn_s_sleep(1);
    }
  }
  __syncthreads();
  __builtin_amdgcn_fence(__ATOMIC_ACQUIRE, "workgroup");  // compiler/order barrier, cheap
}

// Heavy barrier (release store + agent acquire fence -> wbl2/inv). Used ONCE
// after init (publishes normal-stored Xe/H-init AND the counter zero-stores:
// zero-store is program-order before the release flag store; observers do an
// acquire fence after seeing all flags). Flag-based (dword +0), poison-immune.
__device__ __forceinline__ void groupbar_heavy(int* fl, int slot, int ph) {
  __syncthreads();
  if (threadIdx.x == 0)
    __hip_atomic_store(&fl[slot * 32], ph, __ATOMIC_RELEASE, AGENT);
  if (threadIdx.x < 64) {
    for (;;) {
      int v = __hip_atomic_load(&fl[threadIdx.x * 32], __ATOMIC_RELAXED, AGENT);
      if (!__any(v < ph)) break;
      __builtin_amdgcn_s_sleep(1);
    }
  }
  __syncthreads();
  __builtin_amdgcn_fence(__ATOMIC_ACQUIRE, "agent");
}

// One-time all-grid done wait (before the final GEMM). Heavy on purpose: its
// acquire-inv lets the final GEMM use normal cached loads on H1b. Store-then-
// compare -> poison-immune.
__device__ __forceinline__ void donebar(int* dn, int bi) {
  __syncthreads();
  if (threadIdx.x == 0)
    __hip_atomic_store(&dn[bi], 1, __ATOMIC_RELEASE, AGENT);
  for (;;) {
    int v = __hip_atomic_load(&dn[threadIdx.x], __ATOMIC_RELAXED, AGENT);
    if (!__any(v < 1)) break;
    __builtin_amdgcn_s_sleep(1);
  }
  __syncthreads();
  __builtin_amdgcn_fence(__ATOMIC_ACQUIRE, "agent");
}

// Single-cell phase (prologue cell1(0) only; 4 waves, full syncthreads handoff).
__device__ __forceinline__ void cell_phase(char* smem, int offW, int offB, int offC,
                                           const u16* Xt, const u16* Hrec, u16* Hdst,
                                           int g, int c, int w, int lane, int tid) {
  const int r = lane & 15, q = lane >> 4;
  const int row0 = w * 16;
  const u16* xrow = Xt + (size_t)(g * 64 + row0 + r) * EMB_;
  const u16* hrow = Hrec + (size_t)(g * 64 + row0 + r) * HID_;
  const u16* wb = (const u16*)(smem + offW) + lane * 8;
  f32x4 acc0 = {0.f, 0.f, 0.f, 0.f}, acc1 = {0.f, 0.f, 0.f, 0.f};
#pragma unroll
  for (int kb = 0; kb < 8; kb++) {                    // x_t part of K (256)
    s16x8 a  = *(const s16x8*)(xrow + kb * 32 + q * 8);
    s16x8 b0 = *(const s16x8*)(wb + (size_t)(kb * 2 + 0) * 512);
    s16x8 b1 = *(const s16x8*)(wb + (size_t)(kb * 2 + 1) * 512);
    acc0 = mfma16(a, b0, acc0);
    acc1 = mfma16(a, b1, acc1);
  }
  s16x8 ha[16];
  ld_h16(ha, hrow + q * 8);
  waitld();
#pragma unroll
  for (int kb = 0; kb < 16; kb++) {                   // recurrent part of K (512)
    s16x8 b0 = *(const s16x8*)(wb + (size_t)((kb + 8) * 2 + 0) * 512);
    s16x8 b1 = *(const s16x8*)(wb + (size_t)((kb + 8) * 2 + 1) * 512);
    acc0 = mfma16(ha[kb], b0, acc0);
    acc1 = mfma16(ha[kb], b1, acc1);
  }
  float* Ds = (float*)(smem + OFF_DS);
#pragma unroll
  for (int i = 0; i < 4; i++) {
    Ds[(row0 + q * 4 + i) * 33 + r]      = acc0[i];
    Ds[(row0 + q * 4 + i) * 33 + 16 + r] = acc1[i];
  }
  __syncthreads();
  const float* bs = (const float*)(smem + offB);
  float* Cs = (float*)(smem + offC);
  if (tid < 128) {
    int row = tid >> 1, j0 = (tid & 1) * 4;
    union { u16 h[4]; u64 qv; } pk;
#pragma unroll
    for (int i = 0; i < 4; i++) {
      int j = j0 + i;
      float vi = Ds[row * 33 + 0 + j]  + bs[0 + j];
      float vf = Ds[row * 33 + 8 + j]  + bs[8 + j];
      float vo = Ds[row * 33 + 16 + j] + bs[16 + j];
      float vc = Ds[row * 33 + 24 + j] + bs[24 + j];
      float I = sigm(vi), F = sigm(vf), O = sigm(vo), Ct = tanh_(vc);
      float Cn = F * Cs[row * 8 + j] + I * Ct;
      Cs[row * 8 + j] = Cn;
      pk.h[i] = f2bf(O * tanh_(Cn));
    }
    st8_llc(Hdst + (size_t)(g * 64 + row) * HID_ + c * 8 + j0, pk.qv);
  }
}

// cell1 on waves 2-3 only: full gate GEMM + elementwise + H-store, no barrier.
// Wave wv ({0,1} = tid>>6 - 2) owns rows wv*32..+31; scratch handoff is
// intra-wave (lgkmcnt only). Runs entirely PRE-wait inside phase B.
__device__ __forceinline__ void cell1_w23(char* smem, const u16* Xt, const u16* Hrec,
                                          u16* Hdst, int g, int c, int lane, int tid) {
  const int wv = (tid >> 6) - 2;
  const int r = lane & 15, q = lane >> 4;
  const u16* wb1 = (const u16*)(smem + OFF_W1) + lane * 8;
  float* D1 = (float*)(smem + OFF_DS1);
#pragma unroll
  for (int blk = 0; blk < 2; blk++) {
    const int rb = wv * 32 + blk * 16;
    const u16* xrow = Xt + (size_t)(g * 64 + rb + r) * EMB_;
    const u16* hrow = Hrec + (size_t)(g * 64 + rb + r) * HID_;
    s16x8 xa[8];
#pragma unroll
    for (int kb = 0; kb < 8; kb++) xa[kb] = *(const s16x8*)(xrow + kb * 32 + q * 8);
    s16x8 hh[16];
    ld_h16(hh, hrow + q * 8);
    f32x4 a0 = {0.f, 0.f, 0.f, 0.f}, a1 = {0.f, 0.f, 0.f, 0.f};
#pragma unroll
    for (int kb = 0; kb < 8; kb++) {
      a0 = mfma16(xa[kb], *(const s16x8*)(wb1 + (size_t)(kb * 2 + 0) * 512), a0);
      a1 = mfma16(xa[kb], *(const s16x8*)(wb1 + (size_t)(kb * 2 + 1) * 512), a1);
    }
    waitld();
#pragma unroll
    for (int kb = 0; kb < 16; kb++) {
      a0 = mfma16(hh[kb], *(const s16x8*)(wb1 + (size_t)((kb + 8) * 2 + 0) * 512), a0);
      a1 = mfma16(hh[kb], *(const s16x8*)(wb1 + (size_t)((kb + 8) * 2 + 1) * 512), a1);
    }
#pragma unroll
    for (int i = 0; i < 4; i++) {
      D1[(rb + q * 4 + i) * 33 + r]      = a0[i];
      D1[(rb + q * 4 + i) * 33 + 16 + r] = a1[i];
    }
  }
  // elementwise: wave wv reads rows wv*32..+31, which it wrote (intra-wave)
  const float* bs = (const float*)(smem + OFF_B1);
  float* Cs = (float*)(smem + OFF_C);
  int t2 = tid - 128;
  int row = t2 >> 1, j0 = (t2 & 1) * 4;
  union { u16 h[4]; u64 qv; } pk;
#pragma unroll
  for (int i = 0; i < 4; i++) {
    int j = j0 + i;
    float vi = D1[row * 33 + 0 + j]  + bs[0 + j];
    float vf = D1[row * 33 + 8 + j]  + bs[8 + j];
    float vo = D1[row * 33 + 16 + j] + bs[16 + j];
    float vc = D1[row * 33 + 24 + j] + bs[24 + j];
    float I = sigm(vi), F = sigm(vf), O = sigm(vo), Ct = tanh_(vc);
    float Cn = F * Cs[row * 8 + j] + I * Ct;
    Cs[row * 8 + j] = Cn;
    pk.h[i] = f2bf(O * tanh_(Cn));
  }
  st8_llc(Hdst + (size_t)(g * 64 + row) * HID_ + c * 8 + j0, pk.qv);
}

// mix part 1 (pre-wait): acc = H(t+1) @ W_xh  (waves 0-1 only)
__device__ __forceinline__ f32x4 mix_part1(char* smem, const u16* Hnew, int g, int c,
                                           int w, int lane) {
  const int r = lane & 15, q = lane >> 4;
  int rbase = g * 64 + (c & 1) * 32 + w * 16 + r;
  const u16* h0 = Hnew + (size_t)rbase * HID_;
  const u16* wb = (const u16*)(smem + OFF_W2) + lane * 8;
  s16x8 ha[16];
  ld_h16(ha, h0 + q * 8);
  waitld();
  f32x4 acc = {0.f, 0.f, 0.f, 0.f};
#pragma unroll
  for (int kb = 0; kb < 16; kb++)
    acc = mfma16(ha[kb], *(const s16x8*)(wb + (size_t)kb * 512), acc);
  return acc;
}

// mix part 2 (post-wait): acc += H1(t) @ W_hh; sigmoid; store H1m.
// Output transpose via per-wave private LDS (intra-wave, no barrier).
__device__ __forceinline__ void mix_part2(char* smem, f32x4 acc, const u16* H1old,
                                          u16* H1m, int g, int c, int w, int lane) {
  const int r = lane & 15, q = lane >> 4;
  int rbase = g * 64 + (c & 1) * 32 + w * 16 + r;
  const u16* h1 = H1old + (size_t)rbase * HID_;
  const u16* wb = (const u16*)(smem + OFF_W2) + lane * 8;
  s16x8 hb[16];
  ld_h16(hb, h1 + q * 8);
  waitld();
#pragma unroll
  for (int kb = 0; kb < 16; kb++)
    acc = mfma16(hb[kb], *(const s16x8*)(wb + (size_t)(16 + kb) * 512), acc);
  float* Dm = (float*)(smem + OFF_DSM) + (size_t)w * 16 * 17;
#pragma unroll
  for (int i = 0; i < 4; i++) Dm[(q * 4 + i) * 17 + r] = acc[i];
  const float* b2 = (const float*)(smem + OFF_B2);
  int row2 = lane >> 2, j0 = (lane & 3) * 4;
  union { u16 h[4]; u64 qv; } pk;
#pragma unroll
  for (int i = 0; i < 4; i++)
    pk.h[i] = f2bf(sigm(Dm[row2 * 17 + j0 + i] + b2[j0 + i]));
  st8_llc(H1m + (size_t)(g * 64 + (c & 1) * 32 + w * 16 + row2) * HID_ + (c >> 1) * 16 + j0,
          pk.qv);
}

__global__ __launch_bounds__(NTHR, 1) void lstm_pers(Params p) {
  extern __shared__ char smem[];
  const int tid = threadIdx.x;
  const int bi = blockIdx.x;
  const int w = tid >> 6, lane = tid & 63;
  const int g = bi >> 6, c = bi & 63;
  const int r = lane & 15, q = lane >> 4;

  int* fl = (int*)(p.ws + WS_FL) + g * 64 * 32;   // padded: one line per WG
  int* dn = (int*)(p.ws + WS_DONE);
  u16* Hb0 = (u16*)(p.ws + WS_HB0);
  u16* Hb1 = (u16*)(p.ws + WS_HB1);
  u16* H1b = (u16*)(p.ws + WS_H1);
  u16* H1m = (u16*)(p.ws + WS_HM);
  u16* Xe  = (u16*)(p.ws + WS_XE);

  // ---- CRITICAL: zero this group's 8 phase counters (workspace is POISONED,
  // not zeroed, between dispatches; the counter is the only RMW on workspace).
  // Published by groupbar_heavy: zero-store is program-order before the
  // release flag store; every WG acquire-fences after seeing all 64 flags.
  if (tid == 0 && c < 8)
    __hip_atomic_store(&fl[c * 32 + 16], 0, __ATOMIC_RELAXED, AGENT);

  // ---- one-time init: weights -> LDS (bf16, MFMA lane-order swizzle) ----
  {
    u16* w1 = (u16*)(smem + OFF_W1);
    u16* w3 = (u16*)(smem + OFF_W3);
    int gate = tid >> 6, kk8 = (tid >> 3) & 7, j = tid & 7;
    int cc = gate * 8 + j;          // col 0..31 (i0..7,f0..7,o0..7,c0..7)
    int n = cc >> 4, rr = cc & 15;
    int hid = c * 8 + j;
    for (int kk = kk8; kk < 768; kk += 8) {
      int kb = kk >> 5, q2 = (kk >> 3) & 3, e = kk & 7;
      size_t dst = ((size_t)(kb * 2 + n) * 64 + q2 * 16 + rr) * 8 + e;
      float s1 = (kk < 256) ? p.Wx[gate][(size_t)kk * HID_ + hid]
                            : p.Wh[gate][(size_t)(kk - 256) * HID_ + hid];
      float s3 = (kk < 256) ? p.Wx1[gate][(size_t)kk * HID_ + hid]
                            : p.Wh1[gate][(size_t)(kk - 256) * HID_ + hid];
      w1[dst] = f2bf(s1);
      w3[dst] = f2bf(s3);
    }
    {  // mix weights: every WG holds cols (c>>1)*16..+15 (pairs share)
      u16* w2 = (u16*)(smem + OFF_W2);
      int kk16 = tid >> 4, j2 = tid & 15;
      int hid2 = (c >> 1) * 16 + j2;
      for (int kk = kk16; kk < 1024; kk += 16) {
        int kb = kk >> 5, q2 = (kk >> 3) & 3, e = kk & 7;
        size_t dst = ((size_t)kb * 64 + q2 * 16 + j2) * 8 + e;
        float s = (kk < 512) ? p.Wxh[(size_t)kk * HID_ + hid2]
                             : p.Whh[(size_t)(kk - 512) * HID_ + hid2];
        w2[dst] = f2bf(s);
      }
      if (tid < 16) ((float*)(smem + OFF_B2))[tid] = p.bh[(c >> 1) * 16 + tid];
    }
    if (tid < 32) {
      int gt = tid >> 3, jj = tid & 7;
      ((float*)(smem + OFF_B1))[tid] = p.bg[gt][c * 8 + jj];
      ((float*)(smem + OFF_B3))[tid] = p.bg1[gt][c * 8 + jj];
    }
    // C / C1 state (fp32, LDS-resident, WG-local forever)
    float* Cs = (float*)(smem + OFF_C);
    float* C1s = (float*)(smem + OFF_C1);
    for (int it = 0; it < 2; it++) {
      int idx = tid + it * 256;
      int row = idx >> 3, j8 = idx & 7;
      float v = p.Cin[(size_t)(g * 64 + row) * HID_ + c * 8 + j8];
      Cs[row * 8 + j8] = v;
      C1s[row * 8 + j8] = v;
    }
  }
  // H / H1 state init (bf16 in ws, normal stores -> published by heavy barrier)
  // Convention: H(t) lives in Hb[t&1]; H(-1)=Hin in Hb1.
  for (int it = 0; it < 2; it++) {
    int idx = bi * 512 + tid + it * 256;
    u16 hv = f2bf(p.Hin[idx]);
    Hb1[idx] = hv;
    H1b[idx] = hv;
  }
  // Embedding gather, group-local: WG (g,c) fills Xe[t=4c..4c+3][g*64..+63][:]
  for (int tt = 0; tt < 4; tt++) {
    int t0 = c * 4 + tt;
    for (int pp = 0; pp < 16; pp++) {
      int b = g * 64 + w * 16 + pp;
      int tok = p.X[(size_t)b * Tt + t0];
      const float4* er = (const float4*)(p.E + (size_t)tok * EMB_);
      float4 v = er[lane];
      u16x4 u; u.x = f2bf(v.x); u.y = f2bf(v.y); u.z = f2bf(v.z); u.w = f2bf(v.w);
      *(u16x4*)(Xe + ((size_t)t0 * Bb + b) * EMB_ + lane * 4) = u;
    }
  }
  groupbar_heavy(fl, c, 1);   // publish init data + counter zeros (flag-based)

  int cph = 0;   // counted phases (counter barrier)

  // ---- P0: cell1(0): H(-1)=Hb1 -> H(0)=Hb0 ----
  cell_phase(smem, OFF_W1, OFF_B1, OFF_C, Xe, Hb1, Hb0, g, c, w, lane, tid);
  arrive_cnt(fl, c); ++cph;      // cph=1

  // ---- P1: mix(0) [waves 0-1] + cell1(1) [waves 2-3] ----
  wait_cnt(fl, cph);
  if (w < 2) {
    f32x4 macc = mix_part1(smem, Hb0, g, c, w, lane);   // H(0) @ W_xh
    mix_part2(smem, macc, H1b, H1m, g, c, w, lane);     // + H1(-1) @ W_hh
  } else {
    cell1_w23(smem, Xe + (size_t)1 * Bb * EMB_, Hb0, Hb1, g, c, lane, tid);  // H(0)->H(1)
  }
  arrive_cnt(fl, c); ++cph;      // cph=2

  // ---- steady state: 2 thin phases per timestep ----
  for (int t = 0; t < Tt - 1; t++) {
    const u16* Xt = Xe + (size_t)t * Bb * EMB_;
    // ---------- Phase A_t: cell2(t) ----------
    {
      const u16* wb3 = (const u16*)(smem + OFF_W3) + lane * 8;
      const u16* xrow = Xt + (size_t)(g * 64 + w * 16 + r) * EMB_;
      f32x4 acc0 = {0.f, 0.f, 0.f, 0.f}, acc1 = {0.f, 0.f, 0.f, 0.f};
      s16x8 xa[8];
#pragma unroll
      for (int kb = 0; kb < 8; kb++) xa[kb] = *(const s16x8*)(xrow + kb * 32 + q * 8);
#pragma unroll
      for (int kb = 0; kb < 8; kb++) {     // x-part pre-wait
        acc0 = mfma16(xa[kb], *(const s16x8*)(wb3 + (size_t)(kb * 2 + 0) * 512), acc0);
        acc1 = mfma16(xa[kb], *(const s16x8*)(wb3 + (size_t)(kb * 2 + 1) * 512), acc1);
      }
      wait_cnt(fl, cph);                   // need H1m(t) from B_{t-1}
      const u16* hrow = H1m + (size_t)(g * 64 + w * 16 + r) * HID_;
      s16x8 ha[16];
      ld_h16(ha, hrow + q * 8);
      waitld();
#pragma unroll
      for (int kb = 0; kb < 16; kb++) {
        acc0 = mfma16(ha[kb], *(const s16x8*)(wb3 + (size_t)((kb + 8) * 2 + 0) * 512), acc0);
        acc1 = mfma16(ha[kb], *(const s16x8*)(wb3 + (size_t)((kb + 8) * 2 + 1) * 512), acc1);
      }
      float* Ds = (float*)(smem + OFF_DS);
#pragma unroll
      for (int i = 0; i < 4; i++) {
        Ds[(w * 16 + q * 4 + i) * 33 + r]      = acc0[i];
        Ds[(w * 16 + q * 4 + i) * 33 + 16 + r] = acc1[i];
      }
      __syncthreads();
      if (tid < 128) {
        const float* bs = (const float*)(smem + OFF_B3);
        float* Cs = (float*)(smem + OFF_C1);
        int row = tid >> 1, j0 = (tid & 1) * 4;
        union { u16 h[4]; u64 qv; } pk;
#pragma unroll
        for (int i = 0; i < 4; i++) {
          int j = j0 + i;
          float vi = Ds[row * 33 + 0 + j]  + bs[0 + j];
          float vf = Ds[row * 33 + 8 + j]  + bs[8 + j];
          float vo = Ds[row * 33 + 16 + j] + bs[16 + j];
          float vc = Ds[row * 33 + 24 + j] + bs[24 + j];
          float I = sigm(vi), F = sigm(vf), O = sigm(vo), Ct = tanh_(vc);
          float Cn = F * Cs[row * 8 + j] + I * Ct;
          Cs[row * 8 + j] = Cn;
          pk.h[i] = f2bf(O * tanh_(Cn));
        }
        st8_llc(H1b + (size_t)(g * 64 + row) * HID_ + c * 8 + j0, pk.qv);
      }
      arrive_cnt(fl, c); ++cph;
    }
    // ---------- Phase B_t: mix(t+1) [w 0-1] + cell1(t+2) [w 2-3, pre-wait] ----------
    {
      const u16* Hnew = (t & 1) ? Hb0 : Hb1;   // H(t+1)
      u16* Hdst1      = (t & 1) ? Hb1 : Hb0;   // H(t+2)
      f32x4 macc = {0.f, 0.f, 0.f, 0.f};
      if (w < 2) {
        macc = mix_part1(smem, Hnew, g, c, w, lane);        // pre-wait half
      } else if (t + 2 < Tt) {
        cell1_w23(smem, Xe + (size_t)(t + 2) * Bb * EMB_, Hnew, Hdst1, g, c, lane, tid);
      }
      wait_cnt(fl, cph);                     // need H1(t) from A_t
      if (w < 2) mix_part2(smem, macc, H1b, H1m, g, c, w, lane);
      arrive_cnt(fl, c); ++cph;
    }
  }

  // ---- epilogue: cell2(255) ----
  {
    const u16* Xt = Xe + (size_t)(Tt - 1) * Bb * EMB_;
    const u16* wb3 = (const u16*)(smem + OFF_W3) + lane * 8;
    const u16* xrow = Xt + (size_t)(g * 64 + w * 16 + r) * EMB_;
    f32x4 acc0 = {0.f, 0.f, 0.f, 0.f}, acc1 = {0.f, 0.f, 0.f, 0.f};
    s16x8 xa[8];
#pragma unroll
    for (int kb = 0; kb < 8; kb++) xa[kb] = *(const s16x8*)(xrow + kb * 32 + q * 8);
#pragma unroll
    for (int kb = 0; kb < 8; kb++) {
      acc0 = mfma16(xa[kb], *(const s16x8*)(wb3 + (size_t)(kb * 2 + 0) * 512), acc0);
      acc1 = mfma16(xa[kb], *(const s16x8*)(wb3 + (size_t)(kb * 2 + 1) * 512), acc1);
    }
    wait_cnt(fl, cph);                       // mix(255) from B_254
    const u16* hrow = H1m + (size_t)(g * 64 + w * 16 + r) * HID_;
    s16x8 ha[16];
    ld_h16(ha, hrow + q * 8);
    waitld();
#pragma unroll
    for (int kb = 0; kb < 16; kb++) {
      acc0 = mfma16(ha[kb], *(const s16x8*)(wb3 + (size_t)((kb + 8) * 2 + 0) * 512), acc0);
      acc1 = mfma16(ha[kb], *(const s16x8*)(wb3 + (size_t)((kb + 8) * 2 + 1) * 512), acc1);
    }
    float* Ds = (float*)(smem + OFF_DS);
#pragma unroll
    for (int i = 0; i < 4; i++) {
      Ds[(w * 16 + q * 4 + i) * 33 + r]      = acc0[i];
      Ds[(w * 16 + q * 4 + i) * 33 + 16 + r] = acc1[i];
    }
    __syncthreads();
    if (tid < 128) {
      const float* bs = (const float*)(smem + OFF_B3);
      float* Cs = (float*)(smem + OFF_C1);
      int row = tid >> 1, j0 = (tid & 1) * 4;
      union { u16 h[4]; u64 qv; } pk;
#pragma unroll
      for (int i = 0; i < 4; i++) {
        int j = j0 + i;
        float vi = Ds[row * 33 + 0 + j]  + bs[0 + j];
        float vf = Ds[row * 33 + 8 + j]  + bs[8 + j];
        float vo = Ds[row * 33 + 16 + j] + bs[16 + j];
        float vc = Ds[row * 33 + 24 + j] + bs[24 + j];
        float I = sigm(vi), F = sigm(vf), O = sigm(vo), Ct = tanh_(vc);
        float Cn = F * Cs[row * 8 + j] + I * Ct;
        Cs[row * 8 + j] = Cn;
        pk.h[i] = f2bf(O * tanh_(Cn));
      }
      st8_llc(H1b + (size_t)(g * 64 + row) * HID_ + c * 8 + j0, pk.qv);
    }
  }

  // ---- all-groups done (heavy: acquire-inv), then final GEMM with cached loads ----
  donebar(dn, bi);
  if (bi < 250) {
    const int n0 = bi * 128;
    u16* Wf = (u16*)smem;   // reuse weight LDS: [16 kb][8 nt][64 lane][8]
    for (int idx = tid; idx < 512 * 128; idx += NTHR) {
      int k = idx >> 7, nn2 = idx & 127;
      int nt = nn2 >> 4, rr = nn2 & 15;
      int kb = k >> 5, q2 = (k >> 3) & 3, e = k & 7;
      Wf[((size_t)(kb * 8 + nt) * 64 + q2 * 16 + rr) * 8 + e] =
          f2bf(p.Whq[(size_t)k * NCLS + n0 + nn2]);
    }
    float* bqs = (float*)(smem + OFF_C);
    if (tid < 128) bqs[tid] = p.bq[n0 + tid];
    __syncthreads();
    const int r2 = lane & 15, q2 = lane >> 4;
    for (int mt = 0; mt < 4; mt++) {
      int rowb = mt * 64 + w * 16;
      const u16* arow = H1b + (size_t)(rowb + r2) * HID_;
      f32x4 acc[8];
#pragma unroll
      for (int nt = 0; nt < 8; nt++) acc[nt] = (f32x4){0.f, 0.f, 0.f, 0.f};
      for (int kb = 0; kb < 16; kb++) {
        s16x8 a = *(const s16x8*)(arow + kb * 32 + q2 * 8);
#pragma unroll
        for (int nt = 0; nt < 8; nt++) {
          s16x8 b = *(const s16x8*)((const u16*)Wf + ((size_t)(kb * 8 + nt) * 64 + lane) * 8);
          acc[nt] = mfma16(a, b, acc[nt]);
        }
      }
#pragma unroll
      for (int nt = 0; nt < 8; nt++)
#pragma unroll
        for (int i = 0; i < 4; i++)
          p.out[(size_t)(rowb + q2 * 4 + i) * NCLS + n0 + nt * 16 + r2] =
              acc[nt][i] + bqs[nt * 16 + r2];
    }
  }
}

extern "C" void kernel_launch(void* const* d_in, const int* in_sizes, int n_in,
                              void* d_out, int out_size, void* d_ws, size_t ws_size,
                              hipStream_t stream) {
  (void)in_sizes; (void)n_in; (void)out_size; (void)ws_size;
  Params p;
  p.X   = (const int*)d_in[0];
  p.Hin = (const float*)d_in[1];
  p.Cin = (const float*)d_in[2];
  p.E   = (const float*)d_in[3];
  for (int gidx = 0; gidx < 4; gidx++) {   // gate order i,f,o,c
    int base = 4 + gidx * 6;
    p.Wx[gidx]  = (const float*)d_in[base + 0];
    p.Wh[gidx]  = (const float*)d_in[base + 1];
    p.bg[gidx]  = (const float*)d_in[base + 2];
    p.Wx1[gidx] = (const float*)d_in[base + 3];
    p.Wh1[gidx] = (const float*)d_in[base + 4];
    p.bg1[gidx] = (const float*)d_in[base + 5];
  }
  p.Wxh = (const float*)d_in[28];
  p.Whh = (const float*)d_in[29];
  p.bh  = (const float*)d_in[30];
  p.Whq = (const float*)d_in[31];
  p.bq  = (const float*)d_in[32];
  p.out = (float*)d_out;
  p.ws  = (char*)d_ws;

  hipFuncSetAttribute(reinterpret_cast<const void*>(lstm_pers),
                      hipFuncAttributeMaxDynamicSharedMemorySize, SMEM_BYTES);
  lstm_pers<<<dim3(NWG), dim3(NTHR), SMEM_BYTES, stream>>>(p);
}